// Round 1
// baseline (822.487 us; speedup 1.0000x reference)
//
#include <hip/hip_runtime.h>
#include <hip/hip_bf16.h>

#define Bn   8
#define CM_  64
#define CIN  128   // mem(64) + que(64)
#define CO_  64
#define Hn   128
#define Wn   128
#define KSn  3
#define Kn   9
#define COFF 27    // 18 offset + 9 mask channels

// ---------------------------------------------------------------------------
// Kernel 1: offset/mask conv.  off[b][c][h][w] = conv3x3(concat(mem,que), w_off) + b_off
// One thread per (b,h,w) pixel, 27 accumulators. Weight indices are wave-uniform
// -> scalar loads; x neighborhood loads hit L1 (block covers 2 full rows).
// ---------------------------------------------------------------------------
__global__ __launch_bounds__(256) void off_conv_kernel(
    const float* __restrict__ mem, const float* __restrict__ que,
    const float* __restrict__ w_off, const float* __restrict__ b_off,
    float* __restrict__ off)
{
    const int p  = blockIdx.x * 256 + threadIdx.x;   // 0 .. B*H*W-1
    const int b  = p >> 14;                          // / (128*128)
    const int hw = p & 16383;
    const int h  = hw >> 7;
    const int w  = hw & 127;

    float acc[COFF];
    #pragma unroll
    for (int i = 0; i < COFF; ++i) acc[i] = b_off[i];

    for (int c = 0; c < CIN; ++c) {
        const float* src = (c < CM_)
            ? (mem + (size_t)((b * CM_ + c) * Hn) * Wn)
            : (que + (size_t)((b * CM_ + (c - CM_)) * Hn) * Wn);

        float v[9];
        #pragma unroll
        for (int dy = 0; dy < 3; ++dy) {
            const int y = h + dy - 1;
            const bool vy = (y >= 0) & (y < Hn);
            #pragma unroll
            for (int dx = 0; dx < 3; ++dx) {
                const int x = w + dx - 1;
                const bool vx = (x >= 0) & (x < Wn);
                v[dy * 3 + dx] = (vy & vx) ? src[y * Wn + x] : 0.0f;
            }
        }

        const float* wc = w_off + c * 9;   // w_off[co][c][tap]; co stride = CIN*9
        #pragma unroll
        for (int co = 0; co < COFF; ++co) {
            #pragma unroll
            for (int t = 0; t < 9; ++t)
                acc[co] = fmaf(v[t], wc[co * (CIN * 9) + t], acc[co]);
        }
    }

    #pragma unroll
    for (int co = 0; co < COFF; ++co)
        off[(size_t)((b * COFF + co) * Hn + h) * Wn + w] = acc[co];
}

// ---------------------------------------------------------------------------
// Kernel 2: deformable bilinear sampling + einsum over (k,c) -> 64 out channels.
// One thread per (b,h,w); 64 fp32 accumulators. w_def index wave-uniform.
// Bilinear matches the reference exactly: floor, per-corner validity on the
// UNclipped index, clipped gather, weight *= valid, then *= mask.
// ---------------------------------------------------------------------------
__global__ __launch_bounds__(256) void deform_kernel(
    const float* __restrict__ mem, const float* __restrict__ off,
    const float* __restrict__ w_def, float* __restrict__ out)
{
    const int p  = blockIdx.x * 256 + threadIdx.x;
    const int b  = p >> 14;
    const int hw = p & 16383;
    const int h  = hw >> 7;
    const int w  = hw & 127;

    float acc[CO_];
    #pragma unroll
    for (int i = 0; i < CO_; ++i) acc[i] = 0.0f;

    const float* membase = mem + (size_t)b * CM_ * Hn * Wn;
    const float* offbase = off + (size_t)b * COFF * Hn * Wn;
    const int pix = h * Wn + w;

    for (int k = 0; k < Kn; ++k) {
        const float dy = offbase[(2 * k    ) * (Hn * Wn) + pix];
        const float dx = offbase[(2 * k + 1) * (Hn * Wn) + pix];
        const float mk = offbase[(18 + k   ) * (Hn * Wn) + pix];

        const float py = (float)h + (float)(k / 3 - 1) + dy;
        const float px = (float)w + (float)(k % 3 - 1) + dx;
        const float y0f = floorf(py), x0f = floorf(px);
        const float fy = py - y0f,  fx = px - x0f;
        const int y0 = (int)y0f, x0 = (int)x0f;
        const int y1 = y0 + 1,   x1 = x0 + 1;

        const bool vy0 = (y0 >= 0) & (y0 < Hn);
        const bool vy1 = (y1 >= 0) & (y1 < Hn);
        const bool vx0 = (x0 >= 0) & (x0 < Wn);
        const bool vx1 = (x1 >= 0) & (x1 < Wn);

        float w00 = (1.0f - fy) * (1.0f - fx) * (float)(vy0 & vx0) * mk;
        float w01 = (1.0f - fy) * fx          * (float)(vy0 & vx1) * mk;
        float w10 = fy * (1.0f - fx)          * (float)(vy1 & vx0) * mk;
        float w11 = fy * fx                   * (float)(vy1 & vx1) * mk;

        const int y0c = min(max(y0, 0), Hn - 1);
        const int y1c = min(max(y1, 0), Hn - 1);
        const int x0c = min(max(x0, 0), Wn - 1);
        const int x1c = min(max(x1, 0), Wn - 1);

        const int i00 = y0c * Wn + x0c;
        const int i01 = y0c * Wn + x1c;
        const int i10 = y1c * Wn + x0c;
        const int i11 = y1c * Wn + x1c;

        const float* wd = w_def + k;   // w_def[o][c][k]; o stride CM_*Kn, c stride Kn
        const float* mc = membase;
        for (int c = 0; c < CM_; ++c, mc += Hn * Wn) {
            const float s = w00 * mc[i00] + w01 * mc[i01]
                          + w10 * mc[i10] + w11 * mc[i11];
            #pragma unroll
            for (int o = 0; o < CO_; ++o)
                acc[o] = fmaf(s, wd[(o * CM_ + c) * Kn], acc[o]);
        }
    }

    #pragma unroll
    for (int o = 0; o < CO_; ++o)
        out[(size_t)((b * CO_ + o) * Hn + h) * Wn + w] = acc[o];
}

extern "C" void kernel_launch(void* const* d_in, const int* in_sizes, int n_in,
                              void* d_out, int out_size, void* d_ws, size_t ws_size,
                              hipStream_t stream) {
    const float* mem   = (const float*)d_in[0];
    const float* que   = (const float*)d_in[1];
    const float* w_off = (const float*)d_in[2];
    const float* b_off = (const float*)d_in[3];
    const float* w_def = (const float*)d_in[4];
    float* out = (float*)d_out;

    float* off = (float*)d_ws;   // B*27*H*W*4 = 14.2 MB

    const int npix = Bn * Hn * Wn;          // 131072
    const int blocks = npix / 256;          // 512

    off_conv_kernel<<<blocks, 256, 0, stream>>>(mem, que, w_off, b_off, off);
    deform_kernel<<<blocks, 256, 0, stream>>>(mem, off, w_def, out);
}

// Round 2
// 657.172 us; speedup vs baseline: 1.2516x; 1.2516x over previous
//
#include <hip/hip_runtime.h>
#include <hip/hip_bf16.h>

#define Bn   8
#define CM_  64
#define CIN  128   // mem(64) + que(64)
#define CO_  64
#define Hn   128
#define Wn   128
#define Kn   9
#define COFF 27    // 18 offset + 9 mask channels
#define HW   (Hn * Wn)

// ---------------------------------------------------------------------------
// Kernel 1: offset/mask conv, co-split x3 (9 out-channels per thread).
// grid = (512, 3): blockIdx.x & 7 = batch (XCD-L2 affinity), >>3 = pixel blk.
// ---------------------------------------------------------------------------
__global__ __launch_bounds__(256) void off_conv_kernel(
    const float* __restrict__ mem, const float* __restrict__ que,
    const float* __restrict__ w_off, const float* __restrict__ b_off,
    float* __restrict__ off)
{
    const int bb  = blockIdx.x & 7;                       // batch -> XCD
    const int pix = (blockIdx.x >> 3) * 256 + threadIdx.x; // 0..16383
    const int h   = pix >> 7;
    const int w   = pix & 127;
    const int co0 = blockIdx.y * 9;                       // 0, 9, 18

    float acc[9];
    #pragma unroll
    for (int i = 0; i < 9; ++i) acc[i] = b_off[co0 + i];

    // hoisted window validity
    bool vy[3], vx[3];
    #pragma unroll
    for (int d = 0; d < 3; ++d) {
        vy[d] = (h + d - 1 >= 0) & (h + d - 1 < Hn);
        vx[d] = (w + d - 1 >= 0) & (w + d - 1 < Wn);
    }

    for (int c = 0; c < CIN; ++c) {
        const float* src = (c < CM_)
            ? (mem + (size_t)(bb * CM_ + c) * HW)
            : (que + (size_t)(bb * CM_ + (c - CM_)) * HW);

        float v[9];
        #pragma unroll
        for (int dy = 0; dy < 3; ++dy) {
            #pragma unroll
            for (int dx = 0; dx < 3; ++dx) {
                const int idx = (h + dy - 1) * Wn + (w + dx - 1);
                v[dy * 3 + dx] = (vy[dy] & vx[dx]) ? src[idx] : 0.0f;
            }
        }

        const float* wc = w_off + ((size_t)co0 * CIN + c) * 9;
        #pragma unroll
        for (int co = 0; co < 9; ++co) {
            #pragma unroll
            for (int t = 0; t < 9; ++t)
                acc[co] = fmaf(v[t], wc[co * (CIN * 9) + t], acc[co]);
        }
    }

    #pragma unroll
    for (int co = 0; co < 9; ++co)
        off[(size_t)(bb * COFF + co0 + co) * HW + pix] = acc[co];
}

// ---------------------------------------------------------------------------
// Kernel 2: deformable bilinear sampling + einsum, o-split x2 (32 per thread).
// grid = (512, 2): blockIdx.x & 7 = batch (XCD-L2 affinity).
// ---------------------------------------------------------------------------
__global__ __launch_bounds__(256) void deform_kernel(
    const float* __restrict__ mem, const float* __restrict__ off,
    const float* __restrict__ w_def, float* __restrict__ out)
{
    const int bb  = blockIdx.x & 7;
    const int pix = (blockIdx.x >> 3) * 256 + threadIdx.x;
    const int h   = pix >> 7;
    const int w   = pix & 127;
    const int o0  = blockIdx.y * 32;

    float acc[32];
    #pragma unroll
    for (int i = 0; i < 32; ++i) acc[i] = 0.0f;

    const float* membase = mem + (size_t)bb * CM_ * HW;
    const float* offbase = off + (size_t)bb * COFF * HW;

    for (int k = 0; k < Kn; ++k) {
        const float dy = offbase[(2 * k    ) * HW + pix];
        const float dx = offbase[(2 * k + 1) * HW + pix];
        const float mk = offbase[(18 + k   ) * HW + pix];

        const float py = (float)h + (float)(k / 3 - 1) + dy;
        const float px = (float)w + (float)(k % 3 - 1) + dx;
        const float y0f = floorf(py), x0f = floorf(px);
        const float fy = py - y0f,  fx = px - x0f;
        const int y0 = (int)y0f, x0 = (int)x0f;
        const int y1 = y0 + 1,   x1 = x0 + 1;

        const bool vy0 = (y0 >= 0) & (y0 < Hn);
        const bool vy1 = (y1 >= 0) & (y1 < Hn);
        const bool vx0 = (x0 >= 0) & (x0 < Wn);
        const bool vx1 = (x1 >= 0) & (x1 < Wn);

        const float w00 = (1.0f - fy) * (1.0f - fx) * (float)(vy0 & vx0) * mk;
        const float w01 = (1.0f - fy) * fx          * (float)(vy0 & vx1) * mk;
        const float w10 = fy * (1.0f - fx)          * (float)(vy1 & vx0) * mk;
        const float w11 = fy * fx                   * (float)(vy1 & vx1) * mk;

        const int y0c = min(max(y0, 0), Hn - 1);
        const int y1c = min(max(y1, 0), Hn - 1);
        const int x0c = min(max(x0, 0), Wn - 1);
        const int x1c = min(max(x1, 0), Wn - 1);

        const int i00 = y0c * Wn + x0c;
        const int i01 = y0c * Wn + x1c;
        const int i10 = y1c * Wn + x0c;
        const int i11 = y1c * Wn + x1c;

        const float* wd = w_def + (size_t)o0 * CM_ * Kn + k;
        const float* mc = membase;
        for (int c = 0; c < CM_; ++c, mc += HW) {
            const float s = w00 * mc[i00] + w01 * mc[i01]
                          + w10 * mc[i10] + w11 * mc[i11];
            #pragma unroll
            for (int o = 0; o < 32; ++o)
                acc[o] = fmaf(s, wd[(o * CM_ + c) * Kn], acc[o]);
        }
    }

    #pragma unroll
    for (int o = 0; o < 32; ++o)
        out[(size_t)(bb * CO_ + o0 + o) * HW + pix] = acc[o];
}

extern "C" void kernel_launch(void* const* d_in, const int* in_sizes, int n_in,
                              void* d_out, int out_size, void* d_ws, size_t ws_size,
                              hipStream_t stream) {
    const float* mem   = (const float*)d_in[0];
    const float* que   = (const float*)d_in[1];
    const float* w_off = (const float*)d_in[2];
    const float* b_off = (const float*)d_in[3];
    const float* w_def = (const float*)d_in[4];
    float* out = (float*)d_out;

    float* off = (float*)d_ws;   // B*27*H*W*4 = 14.2 MB

    off_conv_kernel<<<dim3(512, 3), 256, 0, stream>>>(mem, que, w_off, b_off, off);
    deform_kernel<<<dim3(512, 2), 256, 0, stream>>>(mem, off, w_def, out);
}

// Round 3
// 440.925 us; speedup vs baseline: 1.8654x; 1.4904x over previous
//
#include <hip/hip_runtime.h>
#include <hip/hip_bf16.h>

#define Bn   8
#define CM_  64
#define CIN  128   // mem(64) + que(64)
#define CO_  64
#define Hn   128
#define Wn   128
#define Kn   9
#define COFF 27    // 18 offset + 9 mask channels
#define HW   (Hn * Wn)

typedef __attribute__((ext_vector_type(8))) short bf16x8;   // 8 bf16 = 4 VGPRs
typedef __attribute__((ext_vector_type(4))) float f32x4;

__device__ __forceinline__ unsigned short f2bf(float x) {   // RNE fp32->bf16
    union { float f; unsigned u; } v; v.f = x;
    unsigned r = v.u + 0x7FFF + ((v.u >> 16) & 1);
    return (unsigned short)(r >> 16);
}

// ---------------------------------------------------------------------------
// Kernel 1: offset/mask conv (unchanged from round 2). fp32 so offsets/masks
// stay exact; only the final contraction is bf16-quantized.
// ---------------------------------------------------------------------------
__global__ __launch_bounds__(256) void off_conv_kernel(
    const float* __restrict__ mem, const float* __restrict__ que,
    const float* __restrict__ w_off, const float* __restrict__ b_off,
    float* __restrict__ off)
{
    const int bb  = blockIdx.x & 7;
    const int pix = (blockIdx.x >> 3) * 256 + threadIdx.x;
    const int h   = pix >> 7;
    const int w   = pix & 127;
    const int co0 = blockIdx.y * 9;

    float acc[9];
    #pragma unroll
    for (int i = 0; i < 9; ++i) acc[i] = b_off[co0 + i];

    bool vy[3], vx[3];
    #pragma unroll
    for (int d = 0; d < 3; ++d) {
        vy[d] = (h + d - 1 >= 0) & (h + d - 1 < Hn);
        vx[d] = (w + d - 1 >= 0) & (w + d - 1 < Wn);
    }

    for (int c = 0; c < CIN; ++c) {
        const float* src = (c < CM_)
            ? (mem + (size_t)(bb * CM_ + c) * HW)
            : (que + (size_t)(bb * CM_ + (c - CM_)) * HW);

        float v[9];
        #pragma unroll
        for (int dy = 0; dy < 3; ++dy)
            #pragma unroll
            for (int dx = 0; dx < 3; ++dx) {
                const int idx = (h + dy - 1) * Wn + (w + dx - 1);
                v[dy * 3 + dx] = (vy[dy] & vx[dx]) ? src[idx] : 0.0f;
            }

        const float* wc = w_off + ((size_t)co0 * CIN + c) * 9;
        #pragma unroll
        for (int co = 0; co < 9; ++co)
            #pragma unroll
            for (int t = 0; t < 9; ++t)
                acc[co] = fmaf(v[t], wc[co * (CIN * 9) + t], acc[co]);
    }

    #pragma unroll
    for (int co = 0; co < 9; ++co)
        off[(size_t)(bb * COFF + co0 + co) * HW + pix] = acc[co];
}

// ---------------------------------------------------------------------------
// Kernel 2: pack w_def into MFMA A-fragment order, bf16.
// ushort index = (((g*9 + k)*2 + f)*64 + L)*8 + j
//   holds W[o = g*16 + (L&15)][c = f*32 + (L>>4)*8 + j] for tap k.
// 36864 elements = 73728 B.
// ---------------------------------------------------------------------------
__global__ __launch_bounds__(256) void wprep_kernel(
    const float* __restrict__ w_def, unsigned short* __restrict__ wp)
{
    const int idx = blockIdx.x * 256 + threadIdx.x;
    if (idx >= CO_ * CM_ * Kn) return;
    const int j  = idx & 7;
    const int L  = (idx >> 3) & 63;
    const int f  = (idx >> 9) & 1;
    const int gk = idx >> 10;          // 0..35
    const int k  = gk % 9;
    const int g  = gk / 9;             // 0..3
    const int o  = g * 16 + (L & 15);
    const int c  = f * 32 + (L >> 4) * 8 + j;
    wp[idx] = f2bf(w_def[(size_t)(o * CM_ + c) * Kn + k]);
}

// ---------------------------------------------------------------------------
// Kernel 3: fused deformable sampling + MFMA GEMM.
// Block = 64-pixel strip x all 64 output channels. Per tap:
//  sampling: thread (cg = tid>>6, pixL = tid&63) gathers 16 channels for its
//            pixel (lanes = consecutive pixels -> coalesced), packs bf16 into
//            LDS tile smp[pix][c] with 16B-chunk XOR swizzle (conflict-free).
//  gemm:     wave g handles o-group g*16..+15: A = weights (global, fragment
//            order), B = samples (LDS), 2 MFMAs x 4 pixel-subtiles.
// D layout (verified m89): row = o = quad*4+reg, col = pixel = lane&15 ->
// coalesced stores.
// ---------------------------------------------------------------------------
__global__ __launch_bounds__(256) void deform_mfma_kernel(
    const float* __restrict__ mem, const float* __restrict__ off,
    const uint4* __restrict__ wprep, float* __restrict__ out)
{
    __shared__ uint4 smp4[64 * 8];     // [pix][chunk^ (pix&7)] : 8 KB

    const int bb   = blockIdx.x & 7;              // batch -> XCD affinity
    const int pix0 = (blockIdx.x >> 3) * 64;      // strip within batch
    const int tid  = threadIdx.x;
    const int pixL = tid & 63;
    const int cg   = tid >> 6;                    // sampling c-group == wave id
    const int lane = tid & 63;
    const int quad = lane >> 4;
    const int lrow = lane & 15;

    const float* membase = mem + (size_t)bb * CM_ * HW;
    const float* offbase = off + (size_t)bb * COFF * HW;

    const int p = pix0 + pixL;
    const int h = p >> 7;
    const int w = p & 127;

    f32x4 acc[4];
    #pragma unroll
    for (int i = 0; i < 4; ++i) acc[i] = (f32x4){0.f, 0.f, 0.f, 0.f};

    for (int k = 0; k < Kn; ++k) {
        // ---------------- sampling phase ----------------
        const float dy = offbase[(2 * k    ) * HW + p];
        const float dx = offbase[(2 * k + 1) * HW + p];
        const float mk = offbase[(18 + k   ) * HW + p];

        const float py = (float)(h + k / 3 - 1) + dy;
        const float px = (float)(w + k % 3 - 1) + dx;
        const float y0f = floorf(py), x0f = floorf(px);
        const float fy = py - y0f,  fx = px - x0f;
        const int y0 = (int)y0f, x0 = (int)x0f;
        const int y1 = y0 + 1,   x1 = x0 + 1;
        const bool vy0 = (y0 >= 0) & (y0 < Hn);
        const bool vy1 = (y1 >= 0) & (y1 < Hn);
        const bool vx0 = (x0 >= 0) & (x0 < Wn);
        const bool vx1 = (x1 >= 0) & (x1 < Wn);
        const float w00 = (1.f - fy) * (1.f - fx) * (float)(vy0 & vx0) * mk;
        const float w01 = (1.f - fy) * fx         * (float)(vy0 & vx1) * mk;
        const float w10 = fy * (1.f - fx)         * (float)(vy1 & vx0) * mk;
        const float w11 = fy * fx                 * (float)(vy1 & vx1) * mk;
        const int y0c = min(max(y0, 0), Hn - 1);
        const int y1c = min(max(y1, 0), Hn - 1);
        const int x0c = min(max(x0, 0), Wn - 1);
        const int x1c = min(max(x1, 0), Wn - 1);
        const int i00 = y0c * Wn + x0c, i01 = y0c * Wn + x1c;
        const int i10 = y1c * Wn + x0c, i11 = y1c * Wn + x1c;

        #pragma unroll
        for (int half = 0; half < 2; ++half) {
            const int cbase = cg * 16 + half * 8;
            unsigned pk[4];
            #pragma unroll
            for (int jj = 0; jj < 4; ++jj) {
                const float* mc0 = membase + (size_t)(cbase + 2 * jj) * HW;
                const float* mc1 = mc0 + HW;
                const float s0 = w00 * mc0[i00] + w01 * mc0[i01]
                               + w10 * mc0[i10] + w11 * mc0[i11];
                const float s1 = w00 * mc1[i00] + w01 * mc1[i01]
                               + w10 * mc1[i10] + w11 * mc1[i11];
                pk[jj] = (unsigned)f2bf(s0) | ((unsigned)f2bf(s1) << 16);
            }
            const int chunk = cg * 2 + half;
            smp4[pixL * 8 + (chunk ^ (pixL & 7))] =
                make_uint4(pk[0], pk[1], pk[2], pk[3]);
        }
        __syncthreads();

        // ---------------- GEMM phase ----------------
        // A (weights) fragments: coalesced 16B loads from fragment-ordered ws.
        const uint4* wpk = wprep + (size_t)((cg * 9 + k) * 2) * 64 + lane;
        const bf16x8 a0 = __builtin_bit_cast(bf16x8, wpk[0]);
        const bf16x8 a1 = __builtin_bit_cast(bf16x8, wpk[64]);

        #pragma unroll
        for (int nt = 0; nt < 4; ++nt) {
            const int pm = nt * 16 + lrow;
            const bf16x8 b0 = __builtin_bit_cast(bf16x8,
                smp4[pm * 8 + ( quad      ^ (pm & 7))]);
            const bf16x8 b1 = __builtin_bit_cast(bf16x8,
                smp4[pm * 8 + ((quad + 4) ^ (pm & 7))]);
            acc[nt] = __builtin_amdgcn_mfma_f32_16x16x32_bf16(a0, b0, acc[nt], 0, 0, 0);
            acc[nt] = __builtin_amdgcn_mfma_f32_16x16x32_bf16(a1, b1, acc[nt], 0, 0, 0);
        }
        __syncthreads();   // before next tap overwrites smp4
    }

    // ---------------- epilogue: D row = o (quad*4+reg), col = pixel ----------
    const int obase = (cg << 4) + (quad << 2);
    #pragma unroll
    for (int nt = 0; nt < 4; ++nt) {
        const int pp = pix0 + nt * 16 + lrow;
        #pragma unroll
        for (int r = 0; r < 4; ++r)
            out[(size_t)(bb * CO_ + obase + r) * HW + pp] = acc[nt][r];
    }
}

extern "C" void kernel_launch(void* const* d_in, const int* in_sizes, int n_in,
                              void* d_out, int out_size, void* d_ws, size_t ws_size,
                              hipStream_t stream) {
    const float* mem   = (const float*)d_in[0];
    const float* que   = (const float*)d_in[1];
    const float* w_off = (const float*)d_in[2];
    const float* b_off = (const float*)d_in[3];
    const float* w_def = (const float*)d_in[4];
    float* out = (float*)d_out;

    float* off = (float*)d_ws;                       // B*27*HW*4 = 14155776 B
    unsigned short* wp = (unsigned short*)((char*)d_ws + (size_t)Bn * COFF * HW * 4);
                                                     // +73728 B, 16B-aligned

    off_conv_kernel<<<dim3(512, 3), 256, 0, stream>>>(mem, que, w_off, b_off, off);
    wprep_kernel<<<144, 256, 0, stream>>>(w_def, wp);
    deform_mfma_kernel<<<2048, 256, 0, stream>>>(mem, off, (const uint4*)wp, out);
}

// Round 4
// 277.612 us; speedup vs baseline: 2.9627x; 1.5883x over previous
//
#include <hip/hip_runtime.h>
#include <hip/hip_bf16.h>

#define Bn   8
#define CM_  64
#define CIN  128   // mem(64) + que(64)
#define CO_  64
#define Hn   128
#define Wn   128
#define Kn   9
#define COFF 27    // 18 offset + 9 mask channels
#define HW   (Hn * Wn)

typedef __attribute__((ext_vector_type(8))) short bf16x8;   // 8 bf16 = 4 VGPRs
typedef __attribute__((ext_vector_type(4))) float f32x4;

__device__ __forceinline__ unsigned short f2bf(float x) {   // RNE fp32->bf16
    union { float f; unsigned u; } v; v.f = x;
    unsigned r = v.u + 0x7FFF + ((v.u >> 16) & 1);
    return (unsigned short)(r >> 16);
}
__device__ __forceinline__ float blo(unsigned u) {
    union { unsigned u; float f; } v; v.u = u << 16; return v.f;
}
__device__ __forceinline__ float bhi(unsigned u) {
    union { unsigned u; float f; } v; v.u = u & 0xffff0000u; return v.f;
}

// ---------------------------------------------------------------------------
// Kernel T: transpose concat(mem,que) [b][c][px] fp32 -> xT[b][px][c] bf16.
// Block: 64-px strip x 128 ch. LDS tile pitch 130 u16 (65 dwords) for
// conflict-free write (u32) and read (b32). Both global sides coalesced.
// ---------------------------------------------------------------------------
__global__ __launch_bounds__(256) void transpose_kernel(
    const float* __restrict__ mem, const float* __restrict__ que,
    uint4* __restrict__ xT4)
{
    __shared__ unsigned tile[64 * 65];   // 64 px rows x 65 dwords (130 bf16)

    const int bb   = blockIdx.x & 7;
    const int pix0 = (blockIdx.x >> 3) * 64;
    const int tid  = threadIdx.x;
    const int pxL  = tid & 63;
    const int cg   = tid >> 6;            // channel group 0..3 (32 ch each)

    const float* mb = mem + (size_t)bb * CM_ * HW + pix0 + pxL;
    const float* qb = que + (size_t)bb * CM_ * HW + pix0 + pxL;

    #pragma unroll
    for (int i = 0; i < 16; ++i) {
        const int c = cg * 32 + 2 * i;
        const float v0 = (c < CM_) ? mb[(size_t)c * HW]       : qb[(size_t)(c - CM_) * HW];
        const float v1 = (c + 1 < CM_) ? mb[(size_t)(c + 1) * HW] : qb[(size_t)(c + 1 - CM_) * HW];
        tile[pxL * 65 + cg * 16 + i] =
            (unsigned)f2bf(v0) | ((unsigned)f2bf(v1) << 16);
    }
    __syncthreads();

    // write out: global uint4 index G = p*256 + tid over the 1024-uint4 tile
    uint4* dst = xT4 + (size_t)(bb * HW + pix0) * 16;
    #pragma unroll
    for (int p = 0; p < 4; ++p) {
        const int G  = p * 256 + tid;     // 0..1023
        const int px = G >> 4;
        const int u  = G & 15;
        uint4 v;
        v.x = tile[px * 65 + u * 4 + 0];
        v.y = tile[px * 65 + u * 4 + 1];
        v.z = tile[px * 65 + u * 4 + 2];
        v.w = tile[px * 65 + u * 4 + 3];
        dst[G] = v;
    }
}

// ---------------------------------------------------------------------------
// Kernel W1: pack w_def into MFMA A-fragment order (bf16), as in round 3.
// ---------------------------------------------------------------------------
__global__ __launch_bounds__(256) void wprep_def_kernel(
    const float* __restrict__ w_def, unsigned short* __restrict__ wp)
{
    const int idx = blockIdx.x * 256 + threadIdx.x;
    if (idx >= CO_ * CM_ * Kn) return;
    const int j  = idx & 7;
    const int L  = (idx >> 3) & 63;
    const int f  = (idx >> 9) & 1;
    const int gk = idx >> 10;
    const int k  = gk % 9;
    const int g  = gk / 9;
    const int o  = g * 16 + (L & 15);
    const int c  = f * 32 + (L >> 4) * 8 + j;
    wp[idx] = f2bf(w_def[(size_t)(o * CM_ + c) * Kn + k]);
}

// ---------------------------------------------------------------------------
// Kernel W2: pack w_off into MFMA A-fragment order (bf16), N padded 27->32.
// linear = (((ot*9+tap)*4+s)*64+L)*8+j ; o = ot*16+(L&15); c = s*32+(L>>4)*8+j.
// ---------------------------------------------------------------------------
__global__ __launch_bounds__(256) void wprep_off_kernel(
    const float* __restrict__ w_off, unsigned short* __restrict__ wp)
{
    const int idx = blockIdx.x * 256 + threadIdx.x;
    if (idx >= 2 * 9 * 4 * 64 * 8) return;
    const int j   = idx & 7;
    const int L   = (idx >> 3) & 63;
    const int s   = (idx >> 9) & 3;
    const int r   = idx >> 11;          // ot*9 + tap
    const int tap = r % 9;
    const int ot  = r / 9;
    const int o   = ot * 16 + (L & 15);
    const int c   = s * 32 + (L >> 4) * 8 + j;
    wp[idx] = (o < COFF) ? f2bf(w_off[(size_t)(o * CIN + c) * Kn + tap]) : (unsigned short)0;
}

// ---------------------------------------------------------------------------
// Kernel 1': offset/mask conv as MFMA GEMM. Block = 64-px strip x 32(=27) out.
// B-fragments straight from global xT (no LDS, no syncthreads).
// Wave w: o-tile = w>>1, pixel-subtiles {2(w&1), 2(w&1)+1}.
// ---------------------------------------------------------------------------
__global__ __launch_bounds__(256) void off_conv_mfma(
    const uint4* __restrict__ xT4, const uint4* __restrict__ wpo,
    const float* __restrict__ b_off, float* __restrict__ off)
{
    const int bb   = blockIdx.x & 7;
    const int pix0 = (blockIdx.x >> 3) * 64;
    const int h    = pix0 >> 7;
    const int w0   = pix0 & 127;
    const int tid  = threadIdx.x;
    const int wv   = tid >> 6;
    const int lane = tid & 63;
    const int quad = lane >> 4;
    const int lrow = lane & 15;
    const int ot   = wv >> 1;
    const int sub0 = (wv & 1) * 2;

    const uint4* xb = xT4 + (size_t)bb * HW * 16;

    f32x4 acc[2];
    #pragma unroll
    for (int t = 0; t < 2; ++t)
        #pragma unroll
        for (int r = 0; r < 4; ++r) {
            const int o = ot * 16 + quad * 4 + r;
            acc[t][r] = (o < COFF) ? b_off[o] : 0.0f;
        }

    for (int tap = 0; tap < 9; ++tap) {
        const int dy = tap / 3 - 1, dx = tap % 3 - 1;
        const bool rowok = (h + dy >= 0) & (h + dy < Hn);

        const uint4* ap = wpo + (size_t)((ot * 9 + tap) * 4) * 64 + lane;
        bf16x8 a[4];
        #pragma unroll
        for (int s = 0; s < 4; ++s) a[s] = __builtin_bit_cast(bf16x8, ap[s * 64]);

        #pragma unroll
        for (int t = 0; t < 2; ++t) {
            const int pl = (sub0 + t) * 16 + lrow;
            const int wc = w0 + pl + dx;
            const bool ok = rowok & (wc >= 0) & (wc < Wn);
            const int ps = ok ? (pix0 + pl + dy * Wn + dx) : 0;
            const uint4* bp = xb + (size_t)ps * 16 + quad;
            uint4 bv[4];
            #pragma unroll
            for (int s = 0; s < 4; ++s) bv[s] = bp[s * 4];
            if (!ok) {
                #pragma unroll
                for (int s = 0; s < 4; ++s) bv[s] = make_uint4(0, 0, 0, 0);
            }
            #pragma unroll
            for (int s = 0; s < 4; ++s)
                acc[t] = __builtin_amdgcn_mfma_f32_16x16x32_bf16(
                    a[s], __builtin_bit_cast(bf16x8, bv[s]), acc[t], 0, 0, 0);
        }
    }

    #pragma unroll
    for (int t = 0; t < 2; ++t) {
        const int pp = pix0 + (sub0 + t) * 16 + lrow;
        #pragma unroll
        for (int r = 0; r < 4; ++r) {
            const int o = ot * 16 + quad * 4 + r;
            if (o < COFF)
                off[(size_t)(bb * COFF + o) * HW + pp] = acc[t][r];
        }
    }
}

// ---------------------------------------------------------------------------
// Kernel 2': fused deformable sampling (bf16 uint4 gathers from xT) + MFMA.
// Structure identical to round 3 except sampling loads 16 ch/corner as uint4
// and blends in fp32 from unpacked bf16.
// ---------------------------------------------------------------------------
__global__ __launch_bounds__(256) void deform_mfma_kernel(
    const uint4* __restrict__ xT4, const float* __restrict__ off,
    const uint4* __restrict__ wprep, float* __restrict__ out)
{
    __shared__ uint4 smp4[64 * 8];     // [pix][chunk ^ (pix&7)] : 8 KB

    const int bb   = blockIdx.x & 7;
    const int pix0 = (blockIdx.x >> 3) * 64;
    const int tid  = threadIdx.x;
    const int pixL = tid & 63;
    const int cg   = tid >> 6;
    const int lane = tid & 63;
    const int quad = lane >> 4;
    const int lrow = lane & 15;

    const uint4*  xb      = xT4 + (size_t)bb * HW * 16;
    const float*  offbase = off + (size_t)bb * COFF * HW;

    const int p = pix0 + pixL;
    const int h = p >> 7;
    const int w = p & 127;

    f32x4 acc[4];
    #pragma unroll
    for (int i = 0; i < 4; ++i) acc[i] = (f32x4){0.f, 0.f, 0.f, 0.f};

    for (int k = 0; k < Kn; ++k) {
        // ---------------- sampling phase ----------------
        const float dy = offbase[(2 * k    ) * HW + p];
        const float dx = offbase[(2 * k + 1) * HW + p];
        const float mk = offbase[(18 + k   ) * HW + p];

        const float py = (float)(h + k / 3 - 1) + dy;
        const float px = (float)(w + k % 3 - 1) + dx;
        const float y0f = floorf(py), x0f = floorf(px);
        const float fy = py - y0f,  fx = px - x0f;
        const int y0 = (int)y0f, x0 = (int)x0f;
        const int y1 = y0 + 1,   x1 = x0 + 1;
        const bool vy0 = (y0 >= 0) & (y0 < Hn);
        const bool vy1 = (y1 >= 0) & (y1 < Hn);
        const bool vx0 = (x0 >= 0) & (x0 < Wn);
        const bool vx1 = (x1 >= 0) & (x1 < Wn);
        const float w00 = (1.f - fy) * (1.f - fx) * (float)(vy0 & vx0) * mk;
        const float w01 = (1.f - fy) * fx         * (float)(vy0 & vx1) * mk;
        const float w10 = fy * (1.f - fx)         * (float)(vy1 & vx0) * mk;
        const float w11 = fy * fx                 * (float)(vy1 & vx1) * mk;
        const int y0c = min(max(y0, 0), Hn - 1);
        const int y1c = min(max(y1, 0), Hn - 1);
        const int x0c = min(max(x0, 0), Wn - 1);
        const int x1c = min(max(x1, 0), Wn - 1);
        const int i00 = y0c * Wn + x0c, i01 = y0c * Wn + x1c;
        const int i10 = y1c * Wn + x0c, i11 = y1c * Wn + x1c;

        #pragma unroll
        for (int half = 0; half < 2; ++half) {
            const int cidx = cg * 2 + half;       // uint4 chunk = 8 channels
            const uint4 v00 = xb[(size_t)i00 * 16 + cidx];
            const uint4 v01 = xb[(size_t)i01 * 16 + cidx];
            const uint4 v10 = xb[(size_t)i10 * 16 + cidx];
            const uint4 v11 = xb[(size_t)i11 * 16 + cidx];
            const unsigned u00[4] = {v00.x, v00.y, v00.z, v00.w};
            const unsigned u01[4] = {v01.x, v01.y, v01.z, v01.w};
            const unsigned u10[4] = {v10.x, v10.y, v10.z, v10.w};
            const unsigned u11[4] = {v11.x, v11.y, v11.z, v11.w};
            unsigned pk[4];
            #pragma unroll
            for (int d = 0; d < 4; ++d) {
                const float slo = w00 * blo(u00[d]) + w01 * blo(u01[d])
                                + w10 * blo(u10[d]) + w11 * blo(u11[d]);
                const float shi = w00 * bhi(u00[d]) + w01 * bhi(u01[d])
                                + w10 * bhi(u10[d]) + w11 * bhi(u11[d]);
                pk[d] = (unsigned)f2bf(slo) | ((unsigned)f2bf(shi) << 16);
            }
            smp4[pixL * 8 + (cidx ^ (pixL & 7))] =
                make_uint4(pk[0], pk[1], pk[2], pk[3]);
        }
        __syncthreads();

        // ---------------- GEMM phase ----------------
        const uint4* wpk = wprep + (size_t)((cg * 9 + k) * 2) * 64 + lane;
        const bf16x8 a0 = __builtin_bit_cast(bf16x8, wpk[0]);
        const bf16x8 a1 = __builtin_bit_cast(bf16x8, wpk[64]);

        #pragma unroll
        for (int nt = 0; nt < 4; ++nt) {
            const int pm = nt * 16 + lrow;
            const bf16x8 b0 = __builtin_bit_cast(bf16x8,
                smp4[pm * 8 + ( quad      ^ (pm & 7))]);
            const bf16x8 b1 = __builtin_bit_cast(bf16x8,
                smp4[pm * 8 + ((quad + 4) ^ (pm & 7))]);
            acc[nt] = __builtin_amdgcn_mfma_f32_16x16x32_bf16(a0, b0, acc[nt], 0, 0, 0);
            acc[nt] = __builtin_amdgcn_mfma_f32_16x16x32_bf16(a1, b1, acc[nt], 0, 0, 0);
        }
        __syncthreads();
    }

    const int obase = (cg << 4) + (quad << 2);
    #pragma unroll
    for (int nt = 0; nt < 4; ++nt) {
        const int pp = pix0 + nt * 16 + lrow;
        #pragma unroll
        for (int r = 0; r < 4; ++r)
            out[(size_t)(bb * CO_ + obase + r) * HW + pp] = acc[nt][r];
    }
}

extern "C" void kernel_launch(void* const* d_in, const int* in_sizes, int n_in,
                              void* d_out, int out_size, void* d_ws, size_t ws_size,
                              hipStream_t stream) {
    const float* mem   = (const float*)d_in[0];
    const float* que   = (const float*)d_in[1];
    const float* w_off = (const float*)d_in[2];
    const float* b_off = (const float*)d_in[3];
    const float* w_def = (const float*)d_in[4];
    float* out = (float*)d_out;

    char* ws = (char*)d_ws;
    float*          off  = (float*)ws;                         // 14,155,776 B
    unsigned short* wpd  = (unsigned short*)(ws + 14155776);   //     73,728 B
    unsigned short* wpo  = (unsigned short*)(ws + 14229504);   //     73,728 B
    uint4*          xT4  = (uint4*)(ws + 14303232);            // 33,554,432 B

    transpose_kernel<<<2048, 256, 0, stream>>>(mem, que, xT4);
    wprep_def_kernel<<<144, 256, 0, stream>>>(w_def, wpd);
    wprep_off_kernel<<<144, 256, 0, stream>>>(w_off, wpo);
    off_conv_mfma<<<2048, 256, 0, stream>>>(xT4, (const uint4*)wpo, b_off, off);
    deform_mfma_kernel<<<2048, 256, 0, stream>>>(xT4, off, (const uint4*)wpd, out);
}

// Round 5
// 220.885 us; speedup vs baseline: 3.7236x; 1.2568x over previous
//
#include <hip/hip_runtime.h>
#include <hip/hip_bf16.h>

#define Bn   8
#define CM_  64
#define CIN  128   // mem(64) + que(64)
#define CO_  64
#define Hn   128
#define Wn   128
#define Kn   9
#define COFF 27    // 18 offset + 9 mask channels
#define HW   (Hn * Wn)

typedef __attribute__((ext_vector_type(8))) short bf16x8;   // 8 bf16 = 4 VGPRs
typedef __attribute__((ext_vector_type(4))) float f32x4;

__device__ __forceinline__ unsigned short f2bf(float x) {   // RNE fp32->bf16
    union { float f; unsigned u; } v; v.f = x;
    unsigned r = v.u + 0x7FFF + ((v.u >> 16) & 1);
    return (unsigned short)(r >> 16);
}
__device__ __forceinline__ float blo(unsigned u) {
    union { unsigned u; float f; } v; v.u = u << 16; return v.f;
}
__device__ __forceinline__ float bhi(unsigned u) {
    union { unsigned u; float f; } v; v.u = u & 0xffff0000u; return v.f;
}

// ---------------------------------------------------------------------------
// Kernel T: transpose concat(mem,que) [b][c][px] fp32 -> xT[b][px][c] bf16.
// ---------------------------------------------------------------------------
__global__ __launch_bounds__(256) void transpose_kernel(
    const float* __restrict__ mem, const float* __restrict__ que,
    uint4* __restrict__ xT4)
{
    __shared__ unsigned tile[64 * 65];

    const int bb   = blockIdx.x & 7;
    const int pix0 = (blockIdx.x >> 3) * 64;
    const int tid  = threadIdx.x;
    const int pxL  = tid & 63;
    const int cg   = tid >> 6;

    const float* mb = mem + (size_t)bb * CM_ * HW + pix0 + pxL;
    const float* qb = que + (size_t)bb * CM_ * HW + pix0 + pxL;

    #pragma unroll
    for (int i = 0; i < 16; ++i) {
        const int c = cg * 32 + 2 * i;
        const float v0 = (c < CM_) ? mb[(size_t)c * HW]       : qb[(size_t)(c - CM_) * HW];
        const float v1 = (c + 1 < CM_) ? mb[(size_t)(c + 1) * HW] : qb[(size_t)(c + 1 - CM_) * HW];
        tile[pxL * 65 + cg * 16 + i] =
            (unsigned)f2bf(v0) | ((unsigned)f2bf(v1) << 16);
    }
    __syncthreads();

    uint4* dst = xT4 + (size_t)(bb * HW + pix0) * 16;
    #pragma unroll
    for (int p = 0; p < 4; ++p) {
        const int G  = p * 256 + tid;
        const int px = G >> 4;
        const int u  = G & 15;
        uint4 v;
        v.x = tile[px * 65 + u * 4 + 0];
        v.y = tile[px * 65 + u * 4 + 1];
        v.z = tile[px * 65 + u * 4 + 2];
        v.w = tile[px * 65 + u * 4 + 3];
        dst[G] = v;
    }
}

// ---------------------------------------------------------------------------
// Kernel W1: pack w_def into MFMA A-fragment order (bf16).
// ---------------------------------------------------------------------------
__global__ __launch_bounds__(256) void wprep_def_kernel(
    const float* __restrict__ w_def, unsigned short* __restrict__ wp)
{
    const int idx = blockIdx.x * 256 + threadIdx.x;
    if (idx >= CO_ * CM_ * Kn) return;
    const int j  = idx & 7;
    const int L  = (idx >> 3) & 63;
    const int f  = (idx >> 9) & 1;
    const int gk = idx >> 10;
    const int k  = gk % 9;
    const int g  = gk / 9;
    const int o  = g * 16 + (L & 15);
    const int c  = f * 32 + (L >> 4) * 8 + j;
    wp[idx] = f2bf(w_def[(size_t)(o * CM_ + c) * Kn + k]);
}

// ---------------------------------------------------------------------------
// Kernel W2: pack w_off into MFMA A-fragment order (bf16), N padded 27->32.
// ---------------------------------------------------------------------------
__global__ __launch_bounds__(256) void wprep_off_kernel(
    const float* __restrict__ w_off, unsigned short* __restrict__ wp)
{
    const int idx = blockIdx.x * 256 + threadIdx.x;
    if (idx >= 2 * 9 * 4 * 64 * 8) return;
    const int j   = idx & 7;
    const int L   = (idx >> 3) & 63;
    const int s   = (idx >> 9) & 3;
    const int r   = idx >> 11;
    const int tap = r % 9;
    const int ot  = r / 9;
    const int o   = ot * 16 + (L & 15);
    const int c   = s * 32 + (L >> 4) * 8 + j;
    wp[idx] = (o < COFF) ? f2bf(w_off[(size_t)(o * CIN + c) * Kn + tap]) : (unsigned short)0;
}

// ---------------------------------------------------------------------------
// Kernel 1'': offset/mask conv as MFMA GEMM with LDS-staged window.
// Block = 64-px strip x 32(=27 padded) outs. Stage rows h-1..h+1, cols
// w0-1..w0+64 (3x66 px) x 128ch bf16 into LDS (50,688 B), coalesced global
// loads + XOR-swizzled chunks. Tap loop: ds_read_b128 B-fragments (no sync,
// no global B-traffic), A from fragment-ordered global (L1-hot).
// ---------------------------------------------------------------------------
__global__ __launch_bounds__(256) void off_conv_mfma(
    const uint4* __restrict__ xT4, const uint4* __restrict__ wpo,
    const float* __restrict__ b_off, float* __restrict__ off)
{
    __shared__ uint4 xw[198 * 16];     // [slot = r*66+c][chunk ^ (slot&7)]

    const int bb   = blockIdx.x & 7;
    const int pix0 = (blockIdx.x >> 3) * 64;
    const int h    = pix0 >> 7;
    const int w0   = pix0 & 127;
    const int tid  = threadIdx.x;
    const int wv   = tid >> 6;
    const int lane = tid & 63;
    const int quad = lane >> 4;
    const int lrow = lane & 15;
    const int ot   = wv >> 1;
    const int sub0 = (wv & 1) * 2;

    const uint4* xb = xT4 + (size_t)bb * HW * 16;

    // ---- stage 3x66-px window (zero-padded) ----
    #pragma unroll
    for (int g = 0; g < 13; ++g) {
        const int idx = g * 256 + tid;
        if (idx < 198 * 16) {
            const int slot = idx >> 4;
            const int j    = idx & 15;
            const int r    = slot / 66;
            const int c    = slot - r * 66;
            const int y    = h + r - 1;
            const int x    = w0 + c - 1;
            const bool ok  = (y >= 0) & (y < Hn) & (x >= 0) & (x < Wn);
            uint4 v = make_uint4(0, 0, 0, 0);
            if (ok) v = xb[(size_t)(y * Wn + x) * 16 + j];
            xw[slot * 16 + (j ^ (slot & 7))] = v;
        }
    }
    __syncthreads();

    f32x4 acc[2];
    #pragma unroll
    for (int t = 0; t < 2; ++t)
        #pragma unroll
        for (int r = 0; r < 4; ++r) {
            const int o = ot * 16 + quad * 4 + r;
            acc[t][r] = (o < COFF) ? b_off[o] : 0.0f;
        }

    #pragma unroll
    for (int tap = 0; tap < 9; ++tap) {
        const int rr = tap / 3;          // window row 0..2
        const int cc = tap % 3;          // col shift 0..2 (c = pl + cc)

        const uint4* ap = wpo + (size_t)((ot * 9 + tap) * 4) * 64 + lane;
        bf16x8 a[4];
        #pragma unroll
        for (int s = 0; s < 4; ++s) a[s] = __builtin_bit_cast(bf16x8, ap[s * 64]);

        #pragma unroll
        for (int t = 0; t < 2; ++t) {
            const int pl   = (sub0 + t) * 16 + lrow;
            const int slot = rr * 66 + pl + cc;
            const int base = slot * 16;
            const int sw   = slot & 7;
            #pragma unroll
            for (int s = 0; s < 4; ++s) {
                const bf16x8 bfrag = __builtin_bit_cast(bf16x8,
                    xw[base + ((s * 4 + quad) ^ sw)]);
                acc[t] = __builtin_amdgcn_mfma_f32_16x16x32_bf16(
                    a[s], bfrag, acc[t], 0, 0, 0);
            }
        }
    }

    #pragma unroll
    for (int t = 0; t < 2; ++t) {
        const int pp = pix0 + (sub0 + t) * 16 + lrow;
        #pragma unroll
        for (int r = 0; r < 4; ++r) {
            const int o = ot * 16 + quad * 4 + r;
            if (o < COFF)
                off[(size_t)(bb * COFF + o) * HW + pp] = acc[t][r];
        }
    }
}

// ---------------------------------------------------------------------------
// Kernel 2': fused deformable sampling (bf16 uint4 gathers from xT) + MFMA.
// (unchanged from round 4)
// ---------------------------------------------------------------------------
__global__ __launch_bounds__(256) void deform_mfma_kernel(
    const uint4* __restrict__ xT4, const float* __restrict__ off,
    const uint4* __restrict__ wprep, float* __restrict__ out)
{
    __shared__ uint4 smp4[64 * 8];

    const int bb   = blockIdx.x & 7;
    const int pix0 = (blockIdx.x >> 3) * 64;
    const int tid  = threadIdx.x;
    const int pixL = tid & 63;
    const int cg   = tid >> 6;
    const int lane = tid & 63;
    const int quad = lane >> 4;
    const int lrow = lane & 15;

    const uint4*  xb      = xT4 + (size_t)bb * HW * 16;
    const float*  offbase = off + (size_t)bb * COFF * HW;

    const int p = pix0 + pixL;
    const int h = p >> 7;
    const int w = p & 127;

    f32x4 acc[4];
    #pragma unroll
    for (int i = 0; i < 4; ++i) acc[i] = (f32x4){0.f, 0.f, 0.f, 0.f};

    for (int k = 0; k < Kn; ++k) {
        const float dy = offbase[(2 * k    ) * HW + p];
        const float dx = offbase[(2 * k + 1) * HW + p];
        const float mk = offbase[(18 + k   ) * HW + p];

        const float py = (float)(h + k / 3 - 1) + dy;
        const float px = (float)(w + k % 3 - 1) + dx;
        const float y0f = floorf(py), x0f = floorf(px);
        const float fy = py - y0f,  fx = px - x0f;
        const int y0 = (int)y0f, x0 = (int)x0f;
        const int y1 = y0 + 1,   x1 = x0 + 1;
        const bool vy0 = (y0 >= 0) & (y0 < Hn);
        const bool vy1 = (y1 >= 0) & (y1 < Hn);
        const bool vx0 = (x0 >= 0) & (x0 < Wn);
        const bool vx1 = (x1 >= 0) & (x1 < Wn);
        const float w00 = (1.f - fy) * (1.f - fx) * (float)(vy0 & vx0) * mk;
        const float w01 = (1.f - fy) * fx         * (float)(vy0 & vx1) * mk;
        const float w10 = fy * (1.f - fx)         * (float)(vy1 & vx0) * mk;
        const float w11 = fy * fx                 * (float)(vy1 & vx1) * mk;
        const int y0c = min(max(y0, 0), Hn - 1);
        const int y1c = min(max(y1, 0), Hn - 1);
        const int x0c = min(max(x0, 0), Wn - 1);
        const int x1c = min(max(x1, 0), Wn - 1);
        const int i00 = y0c * Wn + x0c, i01 = y0c * Wn + x1c;
        const int i10 = y1c * Wn + x0c, i11 = y1c * Wn + x1c;

        #pragma unroll
        for (int half = 0; half < 2; ++half) {
            const int cidx = cg * 2 + half;
            const uint4 v00 = xb[(size_t)i00 * 16 + cidx];
            const uint4 v01 = xb[(size_t)i01 * 16 + cidx];
            const uint4 v10 = xb[(size_t)i10 * 16 + cidx];
            const uint4 v11 = xb[(size_t)i11 * 16 + cidx];
            const unsigned u00[4] = {v00.x, v00.y, v00.z, v00.w};
            const unsigned u01[4] = {v01.x, v01.y, v01.z, v01.w};
            const unsigned u10[4] = {v10.x, v10.y, v10.z, v10.w};
            const unsigned u11[4] = {v11.x, v11.y, v11.z, v11.w};
            unsigned pk[4];
            #pragma unroll
            for (int d = 0; d < 4; ++d) {
                const float slo = w00 * blo(u00[d]) + w01 * blo(u01[d])
                                + w10 * blo(u10[d]) + w11 * blo(u11[d]);
                const float shi = w00 * bhi(u00[d]) + w01 * bhi(u01[d])
                                + w10 * bhi(u10[d]) + w11 * bhi(u11[d]);
                pk[d] = (unsigned)f2bf(slo) | ((unsigned)f2bf(shi) << 16);
            }
            smp4[pixL * 8 + (cidx ^ (pixL & 7))] =
                make_uint4(pk[0], pk[1], pk[2], pk[3]);
        }
        __syncthreads();

        const uint4* wpk = wprep + (size_t)((cg * 9 + k) * 2) * 64 + lane;
        const bf16x8 a0 = __builtin_bit_cast(bf16x8, wpk[0]);
        const bf16x8 a1 = __builtin_bit_cast(bf16x8, wpk[64]);

        #pragma unroll
        for (int nt = 0; nt < 4; ++nt) {
            const int pm = nt * 16 + lrow;
            const bf16x8 b0 = __builtin_bit_cast(bf16x8,
                smp4[pm * 8 + ( quad      ^ (pm & 7))]);
            const bf16x8 b1 = __builtin_bit_cast(bf16x8,
                smp4[pm * 8 + ((quad + 4) ^ (pm & 7))]);
            acc[nt] = __builtin_amdgcn_mfma_f32_16x16x32_bf16(a0, b0, acc[nt], 0, 0, 0);
            acc[nt] = __builtin_amdgcn_mfma_f32_16x16x32_bf16(a1, b1, acc[nt], 0, 0, 0);
        }
        __syncthreads();
    }

    const int obase = (cg << 4) + (quad << 2);
    #pragma unroll
    for (int nt = 0; nt < 4; ++nt) {
        const int pp = pix0 + nt * 16 + lrow;
        #pragma unroll
        for (int r = 0; r < 4; ++r)
            out[(size_t)(bb * CO_ + obase + r) * HW + pp] = acc[nt][r];
    }
}

extern "C" void kernel_launch(void* const* d_in, const int* in_sizes, int n_in,
                              void* d_out, int out_size, void* d_ws, size_t ws_size,
                              hipStream_t stream) {
    const float* mem   = (const float*)d_in[0];
    const float* que   = (const float*)d_in[1];
    const float* w_off = (const float*)d_in[2];
    const float* b_off = (const float*)d_in[3];
    const float* w_def = (const float*)d_in[4];
    float* out = (float*)d_out;

    char* ws = (char*)d_ws;
    float*          off  = (float*)ws;                         // 14,155,776 B
    unsigned short* wpd  = (unsigned short*)(ws + 14155776);   //     73,728 B
    unsigned short* wpo  = (unsigned short*)(ws + 14229504);   //     73,728 B
    uint4*          xT4  = (uint4*)(ws + 14303232);            // 33,554,432 B

    transpose_kernel<<<2048, 256, 0, stream>>>(mem, que, xT4);
    wprep_def_kernel<<<144, 256, 0, stream>>>(w_def, wpd);
    wprep_off_kernel<<<144, 256, 0, stream>>>(w_off, wpo);
    off_conv_mfma<<<2048, 256, 0, stream>>>(xT4, (const uint4*)wpo, b_off, off);
    deform_mfma_kernel<<<2048, 256, 0, stream>>>(xT4, off, (const uint4*)wpd, out);
}

// Round 6
// 195.335 us; speedup vs baseline: 4.2107x; 1.1308x over previous
//
#include <hip/hip_runtime.h>
#include <hip/hip_bf16.h>

#define Bn   8
#define CM_  64
#define CIN  128   // mem(64) + que(64)
#define CO_  64
#define Hn   128
#define Wn   128
#define Kn   9
#define COFF 27    // 18 offset + 9 mask channels
#define HW   (Hn * Wn)

typedef __attribute__((ext_vector_type(8))) short bf16x8;   // 8 bf16 = 4 VGPRs
typedef __attribute__((ext_vector_type(4))) float f32x4;

__device__ __forceinline__ unsigned short f2bf(float x) {   // RNE fp32->bf16
    union { float f; unsigned u; } v; v.f = x;
    unsigned r = v.u + 0x7FFF + ((v.u >> 16) & 1);
    return (unsigned short)(r >> 16);
}
__device__ __forceinline__ float blo(unsigned u) {
    union { unsigned u; float f; } v; v.u = u << 16; return v.f;
}
__device__ __forceinline__ float bhi(unsigned u) {
    union { unsigned u; float f; } v; v.u = u & 0xffff0000u; return v.f;
}

// ---------------------------------------------------------------------------
// Kernel T: transpose concat(mem,que) [b][c][px] fp32 -> xT[b][px][c] bf16.
// ---------------------------------------------------------------------------
__global__ __launch_bounds__(256) void transpose_kernel(
    const float* __restrict__ mem, const float* __restrict__ que,
    uint4* __restrict__ xT4)
{
    __shared__ unsigned tile[64 * 65];

    const int bb   = blockIdx.x & 7;
    const int pix0 = (blockIdx.x >> 3) * 64;
    const int tid  = threadIdx.x;
    const int pxL  = tid & 63;
    const int cg   = tid >> 6;

    const float* mb = mem + (size_t)bb * CM_ * HW + pix0 + pxL;
    const float* qb = que + (size_t)bb * CM_ * HW + pix0 + pxL;

    #pragma unroll
    for (int i = 0; i < 16; ++i) {
        const int c = cg * 32 + 2 * i;
        const float v0 = (c < CM_) ? mb[(size_t)c * HW]       : qb[(size_t)(c - CM_) * HW];
        const float v1 = (c + 1 < CM_) ? mb[(size_t)(c + 1) * HW] : qb[(size_t)(c + 1 - CM_) * HW];
        tile[pxL * 65 + cg * 16 + i] =
            (unsigned)f2bf(v0) | ((unsigned)f2bf(v1) << 16);
    }
    __syncthreads();

    uint4* dst = xT4 + (size_t)(bb * HW + pix0) * 16;
    #pragma unroll
    for (int p = 0; p < 4; ++p) {
        const int G  = p * 256 + tid;
        const int px = G >> 4;
        const int u  = G & 15;
        uint4 v;
        v.x = tile[px * 65 + u * 4 + 0];
        v.y = tile[px * 65 + u * 4 + 1];
        v.z = tile[px * 65 + u * 4 + 2];
        v.w = tile[px * 65 + u * 4 + 3];
        dst[G] = v;
    }
}

// ---------------------------------------------------------------------------
// Kernel W1: pack w_def into MFMA A-fragment order (bf16).
// ---------------------------------------------------------------------------
__global__ __launch_bounds__(256) void wprep_def_kernel(
    const float* __restrict__ w_def, unsigned short* __restrict__ wp)
{
    const int idx = blockIdx.x * 256 + threadIdx.x;
    if (idx >= CO_ * CM_ * Kn) return;
    const int j  = idx & 7;
    const int L  = (idx >> 3) & 63;
    const int f  = (idx >> 9) & 1;
    const int gk = idx >> 10;
    const int k  = gk % 9;
    const int g  = gk / 9;
    const int o  = g * 16 + (L & 15);
    const int c  = f * 32 + (L >> 4) * 8 + j;
    wp[idx] = f2bf(w_def[(size_t)(o * CM_ + c) * Kn + k]);
}

// ---------------------------------------------------------------------------
// Kernel W2: pack w_off into MFMA A-fragment order (bf16), N padded 27->32.
// ---------------------------------------------------------------------------
__global__ __launch_bounds__(256) void wprep_off_kernel(
    const float* __restrict__ w_off, unsigned short* __restrict__ wp)
{
    const int idx = blockIdx.x * 256 + threadIdx.x;
    if (idx >= 2 * 9 * 4 * 64 * 8) return;
    const int j   = idx & 7;
    const int L   = (idx >> 3) & 63;
    const int s   = (idx >> 9) & 3;
    const int r   = idx >> 11;
    const int tap = r % 9;
    const int ot  = r / 9;
    const int o   = ot * 16 + (L & 15);
    const int c   = s * 32 + (L >> 4) * 8 + j;
    wp[idx] = (o < COFF) ? f2bf(w_off[(size_t)(o * CIN + c) * Kn + tap]) : (unsigned short)0;
}

// ---------------------------------------------------------------------------
// Kernel 1'': offset/mask conv as MFMA GEMM with LDS-staged window.
// (unchanged from round 5)
// ---------------------------------------------------------------------------
__global__ __launch_bounds__(256) void off_conv_mfma(
    const uint4* __restrict__ xT4, const uint4* __restrict__ wpo,
    const float* __restrict__ b_off, float* __restrict__ off)
{
    __shared__ uint4 xw[198 * 16];     // [slot = r*66+c][chunk ^ (slot&7)]

    const int bb   = blockIdx.x & 7;
    const int pix0 = (blockIdx.x >> 3) * 64;
    const int h    = pix0 >> 7;
    const int w0   = pix0 & 127;
    const int tid  = threadIdx.x;
    const int wv   = tid >> 6;
    const int lane = tid & 63;
    const int quad = lane >> 4;
    const int lrow = lane & 15;
    const int ot   = wv >> 1;
    const int sub0 = (wv & 1) * 2;

    const uint4* xb = xT4 + (size_t)bb * HW * 16;

    #pragma unroll
    for (int g = 0; g < 13; ++g) {
        const int idx = g * 256 + tid;
        if (idx < 198 * 16) {
            const int slot = idx >> 4;
            const int j    = idx & 15;
            const int r    = slot / 66;
            const int c    = slot - r * 66;
            const int y    = h + r - 1;
            const int x    = w0 + c - 1;
            const bool ok  = (y >= 0) & (y < Hn) & (x >= 0) & (x < Wn);
            uint4 v = make_uint4(0, 0, 0, 0);
            if (ok) v = xb[(size_t)(y * Wn + x) * 16 + j];
            xw[slot * 16 + (j ^ (slot & 7))] = v;
        }
    }
    __syncthreads();

    f32x4 acc[2];
    #pragma unroll
    for (int t = 0; t < 2; ++t)
        #pragma unroll
        for (int r = 0; r < 4; ++r) {
            const int o = ot * 16 + quad * 4 + r;
            acc[t][r] = (o < COFF) ? b_off[o] : 0.0f;
        }

    #pragma unroll
    for (int tap = 0; tap < 9; ++tap) {
        const int rr = tap / 3;
        const int cc = tap % 3;

        const uint4* ap = wpo + (size_t)((ot * 9 + tap) * 4) * 64 + lane;
        bf16x8 a[4];
        #pragma unroll
        for (int s = 0; s < 4; ++s) a[s] = __builtin_bit_cast(bf16x8, ap[s * 64]);

        #pragma unroll
        for (int t = 0; t < 2; ++t) {
            const int pl   = (sub0 + t) * 16 + lrow;
            const int slot = rr * 66 + pl + cc;
            const int base = slot * 16;
            const int sw   = slot & 7;
            #pragma unroll
            for (int s = 0; s < 4; ++s) {
                const bf16x8 bfrag = __builtin_bit_cast(bf16x8,
                    xw[base + ((s * 4 + quad) ^ sw)]);
                acc[t] = __builtin_amdgcn_mfma_f32_16x16x32_bf16(
                    a[s], bfrag, acc[t], 0, 0, 0);
            }
        }
    }

    #pragma unroll
    for (int t = 0; t < 2; ++t) {
        const int pp = pix0 + (sub0 + t) * 16 + lrow;
        #pragma unroll
        for (int r = 0; r < 4; ++r) {
            const int o = ot * 16 + quad * 4 + r;
            if (o < COFF)
                off[(size_t)(bb * COFF + o) * HW + pp] = acc[t][r];
        }
    }
}

// ---------------------------------------------------------------------------
// Kernel 2'': fused deformable sampling + MFMA, channel-major gather lanes.
// Sampling: lane = (psub = lane>>3, chunk = lane&7). Wave wv, group g covers
// pixels pl = g*32 + wv*8 + psub. Each corner load instr covers 8 positions
// x 128 B contiguous (~8 cache lines vs 64 in the pixel-major mapping).
// Weights computed redundantly by the 8 lanes sharing a pixel (broadcast
// off[] reads). Blended uint4 written straight into the swizzled smp tile.
// MFMA phase and epilogue unchanged.
// ---------------------------------------------------------------------------
__global__ __launch_bounds__(256) void deform_mfma_kernel(
    const uint4* __restrict__ xT4, const float* __restrict__ off,
    const uint4* __restrict__ wprep, float* __restrict__ out)
{
    __shared__ uint4 smp4[64 * 8];     // [pix][chunk ^ (pix&7)] : 8 KB

    const int bb    = blockIdx.x & 7;
    const int pix0  = (blockIdx.x >> 3) * 64;
    const int tid   = threadIdx.x;
    const int wv    = tid >> 6;        // wave id (= cg for MFMA phase)
    const int lane  = tid & 63;
    const int quad  = lane >> 4;
    const int lrow  = lane & 15;
    const int chunk = lane & 7;        // 8 channels per chunk
    const int psub  = lane >> 3;       // 0..7

    const uint4*  xb      = xT4 + (size_t)bb * HW * 16;
    const float*  offbase = off + (size_t)bb * COFF * HW;

    f32x4 acc[4];
    #pragma unroll
    for (int i = 0; i < 4; ++i) acc[i] = (f32x4){0.f, 0.f, 0.f, 0.f};

    for (int k = 0; k < Kn; ++k) {
        // ---------------- sampling phase (channel-major lanes) ----------------
        #pragma unroll
        for (int g = 0; g < 2; ++g) {
            const int pl = g * 32 + wv * 8 + psub;   // 0..63, covered once
            const int p  = pix0 + pl;
            const int h  = p >> 7;
            const int w  = p & 127;

            const float dy = offbase[(2 * k    ) * HW + p];
            const float dx = offbase[(2 * k + 1) * HW + p];
            const float mk = offbase[(18 + k   ) * HW + p];

            const float py = (float)(h + k / 3 - 1) + dy;
            const float px = (float)(w + k % 3 - 1) + dx;
            const float y0f = floorf(py), x0f = floorf(px);
            const float fy = py - y0f,  fx = px - x0f;
            const int y0 = (int)y0f, x0 = (int)x0f;
            const int y1 = y0 + 1,   x1 = x0 + 1;
            const bool vy0 = (y0 >= 0) & (y0 < Hn);
            const bool vy1 = (y1 >= 0) & (y1 < Hn);
            const bool vx0 = (x0 >= 0) & (x0 < Wn);
            const bool vx1 = (x1 >= 0) & (x1 < Wn);
            const float w00 = (1.f - fy) * (1.f - fx) * (float)(vy0 & vx0) * mk;
            const float w01 = (1.f - fy) * fx         * (float)(vy0 & vx1) * mk;
            const float w10 = fy * (1.f - fx)         * (float)(vy1 & vx0) * mk;
            const float w11 = fy * fx                 * (float)(vy1 & vx1) * mk;
            const int y0c = min(max(y0, 0), Hn - 1);
            const int y1c = min(max(y1, 0), Hn - 1);
            const int x0c = min(max(x0, 0), Wn - 1);
            const int x1c = min(max(x1, 0), Wn - 1);
            const int i00 = y0c * Wn + x0c, i01 = y0c * Wn + x1c;
            const int i10 = y1c * Wn + x0c, i11 = y1c * Wn + x1c;

            const uint4 v00 = xb[(size_t)i00 * 16 + chunk];
            const uint4 v01 = xb[(size_t)i01 * 16 + chunk];
            const uint4 v10 = xb[(size_t)i10 * 16 + chunk];
            const uint4 v11 = xb[(size_t)i11 * 16 + chunk];
            const unsigned u00[4] = {v00.x, v00.y, v00.z, v00.w};
            const unsigned u01[4] = {v01.x, v01.y, v01.z, v01.w};
            const unsigned u10[4] = {v10.x, v10.y, v10.z, v10.w};
            const unsigned u11[4] = {v11.x, v11.y, v11.z, v11.w};
            unsigned pk[4];
            #pragma unroll
            for (int d = 0; d < 4; ++d) {
                const float slo = w00 * blo(u00[d]) + w01 * blo(u01[d])
                                + w10 * blo(u10[d]) + w11 * blo(u11[d]);
                const float shi = w00 * bhi(u00[d]) + w01 * bhi(u01[d])
                                + w10 * bhi(u10[d]) + w11 * bhi(u11[d]);
                pk[d] = (unsigned)f2bf(slo) | ((unsigned)f2bf(shi) << 16);
            }
            smp4[pl * 8 + (chunk ^ (pl & 7))] =
                make_uint4(pk[0], pk[1], pk[2], pk[3]);
        }
        __syncthreads();

        // ---------------- GEMM phase ----------------
        const uint4* wpk = wprep + (size_t)((wv * 9 + k) * 2) * 64 + lane;
        const bf16x8 a0 = __builtin_bit_cast(bf16x8, wpk[0]);
        const bf16x8 a1 = __builtin_bit_cast(bf16x8, wpk[64]);

        #pragma unroll
        for (int nt = 0; nt < 4; ++nt) {
            const int pm = nt * 16 + lrow;
            const bf16x8 b0 = __builtin_bit_cast(bf16x8,
                smp4[pm * 8 + ( quad      ^ (pm & 7))]);
            const bf16x8 b1 = __builtin_bit_cast(bf16x8,
                smp4[pm * 8 + ((quad + 4) ^ (pm & 7))]);
            acc[nt] = __builtin_amdgcn_mfma_f32_16x16x32_bf16(a0, b0, acc[nt], 0, 0, 0);
            acc[nt] = __builtin_amdgcn_mfma_f32_16x16x32_bf16(a1, b1, acc[nt], 0, 0, 0);
        }
        __syncthreads();
    }

    const int obase = (wv << 4) + (quad << 2);
    #pragma unroll
    for (int nt = 0; nt < 4; ++nt) {
        const int pp = pix0 + nt * 16 + lrow;
        #pragma unroll
        for (int r = 0; r < 4; ++r)
            out[(size_t)(bb * CO_ + obase + r) * HW + pp] = acc[nt][r];
    }
}

extern "C" void kernel_launch(void* const* d_in, const int* in_sizes, int n_in,
                              void* d_out, int out_size, void* d_ws, size_t ws_size,
                              hipStream_t stream) {
    const float* mem   = (const float*)d_in[0];
    const float* que   = (const float*)d_in[1];
    const float* w_off = (const float*)d_in[2];
    const float* b_off = (const float*)d_in[3];
    const float* w_def = (const float*)d_in[4];
    float* out = (float*)d_out;

    char* ws = (char*)d_ws;
    float*          off  = (float*)ws;                         // 14,155,776 B
    unsigned short* wpd  = (unsigned short*)(ws + 14155776);   //     73,728 B
    unsigned short* wpo  = (unsigned short*)(ws + 14229504);   //     73,728 B
    uint4*          xT4  = (uint4*)(ws + 14303232);            // 33,554,432 B

    transpose_kernel<<<2048, 256, 0, stream>>>(mem, que, xT4);
    wprep_def_kernel<<<144, 256, 0, stream>>>(w_def, wpd);
    wprep_off_kernel<<<144, 256, 0, stream>>>(w_off, wpo);
    off_conv_mfma<<<2048, 256, 0, stream>>>(xT4, (const uint4*)wpo, b_off, off);
    deform_mfma_kernel<<<2048, 256, 0, stream>>>(xT4, off, (const uint4*)wpd, out);
}

// Round 8
// 185.910 us; speedup vs baseline: 4.4241x; 1.0507x over previous
//
#include <hip/hip_runtime.h>
#include <hip/hip_bf16.h>

#define Bn   8
#define CM_  64
#define CIN  128   // mem(64) + que(64)
#define CO_  64
#define Hn   128
#define Wn   128
#define Kn   9
#define COFF 27    // 18 offset + 9 mask channels
#define HW   (Hn * Wn)

typedef __attribute__((ext_vector_type(8))) short bf16x8;   // 8 bf16 = 4 VGPRs
typedef __attribute__((ext_vector_type(4))) float f32x4;
typedef __attribute__((ext_vector_type(2))) float f32x2;

__device__ __forceinline__ unsigned short f2bf(float x) {   // RNE fp32->bf16
    union { float f; unsigned u; } v; v.f = x;
    unsigned r = v.u + 0x7FFF + ((v.u >> 16) & 1);
    return (unsigned short)(r >> 16);
}
__device__ __forceinline__ float blo(unsigned u) {
    union { unsigned u; float f; } v; v.u = u << 16; return v.f;
}
__device__ __forceinline__ float bhi(unsigned u) {
    union { unsigned u; float f; } v; v.u = u & 0xffff0000u; return v.f;
}
__device__ __forceinline__ unsigned pack_bf2(float lo, float hi) {
    __hip_bfloat162 r = __float22bfloat162_rn(make_float2(lo, hi));
    unsigned u;
    __builtin_memcpy(&u, &r, 4);        // v_cvt_pk_bf16_f32 + reg move
    return u;
}

// ---------------------------------------------------------------------------
// Kernel T: transpose concat(mem,que) [b][c][px] fp32 -> xT[b][px][c] bf16.
// ---------------------------------------------------------------------------
__global__ __launch_bounds__(256) void transpose_kernel(
    const float* __restrict__ mem, const float* __restrict__ que,
    uint4* __restrict__ xT4)
{
    __shared__ unsigned tile[64 * 65];

    const int bb   = blockIdx.x & 7;
    const int pix0 = (blockIdx.x >> 3) * 64;
    const int tid  = threadIdx.x;
    const int pxL  = tid & 63;
    const int cg   = tid >> 6;

    const float* mb = mem + (size_t)bb * CM_ * HW + pix0 + pxL;
    const float* qb = que + (size_t)bb * CM_ * HW + pix0 + pxL;

    #pragma unroll
    for (int i = 0; i < 16; ++i) {
        const int c = cg * 32 + 2 * i;
        const float v0 = (c < CM_) ? mb[(size_t)c * HW]       : qb[(size_t)(c - CM_) * HW];
        const float v1 = (c + 1 < CM_) ? mb[(size_t)(c + 1) * HW] : qb[(size_t)(c + 1 - CM_) * HW];
        tile[pxL * 65 + cg * 16 + i] =
            (unsigned)f2bf(v0) | ((unsigned)f2bf(v1) << 16);
    }
    __syncthreads();

    uint4* dst = xT4 + (size_t)(bb * HW + pix0) * 16;
    #pragma unroll
    for (int p = 0; p < 4; ++p) {
        const int G  = p * 256 + tid;
        const int px = G >> 4;
        const int u  = G & 15;
        uint4 v;
        v.x = tile[px * 65 + u * 4 + 0];
        v.y = tile[px * 65 + u * 4 + 1];
        v.z = tile[px * 65 + u * 4 + 2];
        v.w = tile[px * 65 + u * 4 + 3];
        dst[G] = v;
    }
}

// ---------------------------------------------------------------------------
// Kernel W1: pack w_def into MFMA A-fragment order (bf16).
// ---------------------------------------------------------------------------
__global__ __launch_bounds__(256) void wprep_def_kernel(
    const float* __restrict__ w_def, unsigned short* __restrict__ wp)
{
    const int idx = blockIdx.x * 256 + threadIdx.x;
    if (idx >= CO_ * CM_ * Kn) return;
    const int j  = idx & 7;
    const int L  = (idx >> 3) & 63;
    const int f  = (idx >> 9) & 1;
    const int gk = idx >> 10;
    const int k  = gk % 9;
    const int g  = gk / 9;
    const int o  = g * 16 + (L & 15);
    const int c  = f * 32 + (L >> 4) * 8 + j;
    wp[idx] = f2bf(w_def[(size_t)(o * CM_ + c) * Kn + k]);
}

// ---------------------------------------------------------------------------
// Kernel W2: pack w_off into MFMA A-fragment order (bf16), N padded 27->32.
// ---------------------------------------------------------------------------
__global__ __launch_bounds__(256) void wprep_off_kernel(
    const float* __restrict__ w_off, unsigned short* __restrict__ wp)
{
    const int idx = blockIdx.x * 256 + threadIdx.x;
    if (idx >= 2 * 9 * 4 * 64 * 8) return;
    const int j   = idx & 7;
    const int L   = (idx >> 3) & 63;
    const int s   = (idx >> 9) & 3;
    const int r   = idx >> 11;
    const int tap = r % 9;
    const int ot  = r / 9;
    const int o   = ot * 16 + (L & 15);
    const int c   = s * 32 + (L >> 4) * 8 + j;
    wp[idx] = (o < COFF) ? f2bf(w_off[(size_t)(o * CIN + c) * Kn + tap]) : (unsigned short)0;
}

// ---------------------------------------------------------------------------
// Kernel 1'': offset/mask conv as MFMA GEMM with LDS-staged window.
// (unchanged from round 5/6)
// ---------------------------------------------------------------------------
__global__ __launch_bounds__(256) void off_conv_mfma(
    const uint4* __restrict__ xT4, const uint4* __restrict__ wpo,
    const float* __restrict__ b_off, float* __restrict__ off)
{
    __shared__ uint4 xw[198 * 16];     // [slot = r*66+c][chunk ^ (slot&7)]

    const int bb   = blockIdx.x & 7;
    const int pix0 = (blockIdx.x >> 3) * 64;
    const int h    = pix0 >> 7;
    const int w0   = pix0 & 127;
    const int tid  = threadIdx.x;
    const int wv   = tid >> 6;
    const int lane = tid & 63;
    const int quad = lane >> 4;
    const int lrow = lane & 15;
    const int ot   = wv >> 1;
    const int sub0 = (wv & 1) * 2;

    const uint4* xb = xT4 + (size_t)bb * HW * 16;

    #pragma unroll
    for (int g = 0; g < 13; ++g) {
        const int idx = g * 256 + tid;
        if (idx < 198 * 16) {
            const int slot = idx >> 4;
            const int j    = idx & 15;
            const int r    = slot / 66;
            const int c    = slot - r * 66;
            const int y    = h + r - 1;
            const int x    = w0 + c - 1;
            const bool ok  = (y >= 0) & (y < Hn) & (x >= 0) & (x < Wn);
            uint4 v = make_uint4(0, 0, 0, 0);
            if (ok) v = xb[(size_t)(y * Wn + x) * 16 + j];
            xw[slot * 16 + (j ^ (slot & 7))] = v;
        }
    }
    __syncthreads();

    f32x4 acc[2];
    #pragma unroll
    for (int t = 0; t < 2; ++t)
        #pragma unroll
        for (int r = 0; r < 4; ++r) {
            const int o = ot * 16 + quad * 4 + r;
            acc[t][r] = (o < COFF) ? b_off[o] : 0.0f;
        }

    #pragma unroll
    for (int tap = 0; tap < 9; ++tap) {
        const int rr = tap / 3;
        const int cc = tap % 3;

        const uint4* ap = wpo + (size_t)((ot * 9 + tap) * 4) * 64 + lane;
        bf16x8 a[4];
        #pragma unroll
        for (int s = 0; s < 4; ++s) a[s] = __builtin_bit_cast(bf16x8, ap[s * 64]);

        #pragma unroll
        for (int t = 0; t < 2; ++t) {
            const int pl   = (sub0 + t) * 16 + lrow;
            const int slot = rr * 66 + pl + cc;
            const int base = slot * 16;
            const int sw   = slot & 7;
            #pragma unroll
            for (int s = 0; s < 4; ++s) {
                const bf16x8 bfrag = __builtin_bit_cast(bf16x8,
                    xw[base + ((s * 4 + quad) ^ sw)]);
                acc[t] = __builtin_amdgcn_mfma_f32_16x16x32_bf16(
                    a[s], bfrag, acc[t], 0, 0, 0);
            }
        }
    }

    #pragma unroll
    for (int t = 0; t < 2; ++t) {
        const int pp = pix0 + (sub0 + t) * 16 + lrow;
        #pragma unroll
        for (int r = 0; r < 4; ++r) {
            const int o = ot * 16 + quad * 4 + r;
            if (o < COFF)
                off[(size_t)(bb * COFF + o) * HW + pp] = acc[t][r];
        }
    }
}

// ---------------------------------------------------------------------------
// Kernel 2''': deform + MFMA, v3.
//  - weights/indices computed pixel-major once per wave (lane = pixel),
//    moved to channel-major lanes via __shfl (8 bpermutes per g-group)
//  - gathers issued BEFORE the MFMA phase of the previous tap (latency hidden)
//  - blend in f32x2 packed math, pack via v_cvt_pk_bf16_f32
//  - double-buffered smp tile -> ONE barrier per tap
// ---------------------------------------------------------------------------
__global__ __launch_bounds__(256) void deform_mfma_kernel(
    const uint4* __restrict__ xT4, const float* __restrict__ off,
    const uint4* __restrict__ wprep, float* __restrict__ out)
{
    __shared__ uint4 smp4[2][64 * 8];   // [buf][pix][chunk ^ (pix&7)] : 16 KB

    const int bb    = blockIdx.x & 7;
    const int pix0  = (blockIdx.x >> 3) * 64;
    const int tid   = threadIdx.x;
    const int wv    = tid >> 6;
    const int lane  = tid & 63;
    const int quad  = lane >> 4;
    const int lrow  = lane & 15;
    const int chunk = lane & 7;
    const int psub  = lane >> 3;

    const uint4*  xb      = xT4 + (size_t)bb * HW * 16;
    const float*  offbase = off + (size_t)bb * COFF * HW;

    // pixel-major identity for weight computation (lane = pixel)
    const int pM = pix0 + lane;
    const int hM = pM >> 7;
    const int wM = pM & 127;

    f32x4 acc[4];
    #pragma unroll
    for (int i = 0; i < 4; ++i) acc[i] = (f32x4){0.f, 0.f, 0.f, 0.f};

    // regs carried from prep -> blendwrite
    float W00[2], W01[2], W10[2], W11[2];
    uint4 G00[2], G01[2], G10[2], G11[2];

    auto prep = [&](int k) {
        // ---- pixel-major: weights + corner indices for pixel pM ----
        const float dy = offbase[(2 * k    ) * HW + pM];
        const float dx = offbase[(2 * k + 1) * HW + pM];
        const float mk = offbase[(18 + k   ) * HW + pM];
        const float py = (float)(hM + k / 3 - 1) + dy;
        const float px = (float)(wM + k % 3 - 1) + dx;
        const float y0f = floorf(py), x0f = floorf(px);
        const float fy = py - y0f,  fx = px - x0f;
        const int y0 = (int)y0f, x0 = (int)x0f;
        const int y1 = y0 + 1,   x1 = x0 + 1;
        const bool vy0 = (y0 >= 0) & (y0 < Hn);
        const bool vy1 = (y1 >= 0) & (y1 < Hn);
        const bool vx0 = (x0 >= 0) & (x0 < Wn);
        const bool vx1 = (x1 >= 0) & (x1 < Wn);
        const float w00 = (1.f - fy) * (1.f - fx) * (float)(vy0 & vx0) * mk;
        const float w01 = (1.f - fy) * fx         * (float)(vy0 & vx1) * mk;
        const float w10 = fy * (1.f - fx)         * (float)(vy1 & vx0) * mk;
        const float w11 = fy * fx                 * (float)(vy1 & vx1) * mk;
        const int y0c = min(max(y0, 0), Hn - 1);
        const int y1c = min(max(y1, 0), Hn - 1);
        const int x0c = min(max(x0, 0), Wn - 1);
        const int x1c = min(max(x1, 0), Wn - 1);
        const int i00 = y0c * Wn + x0c, i01 = y0c * Wn + x1c;
        const int i10 = y1c * Wn + x0c, i11 = y1c * Wn + x1c;

        // ---- shuffle to channel-major lanes + issue gathers ----
        #pragma unroll
        for (int g = 0; g < 2; ++g) {
            const int pl = g * 32 + wv * 8 + psub;
            W00[g] = __shfl(w00, pl, 64);
            W01[g] = __shfl(w01, pl, 64);
            W10[g] = __shfl(w10, pl, 64);
            W11[g] = __shfl(w11, pl, 64);
            const int I00 = __shfl(i00, pl, 64);
            const int I01 = __shfl(i01, pl, 64);
            const int I10 = __shfl(i10, pl, 64);
            const int I11 = __shfl(i11, pl, 64);
            G00[g] = xb[(size_t)I00 * 16 + chunk];
            G01[g] = xb[(size_t)I01 * 16 + chunk];
            G10[g] = xb[(size_t)I10 * 16 + chunk];
            G11[g] = xb[(size_t)I11 * 16 + chunk];
        }
    };

    auto blendwrite = [&](int buf) {
        #pragma unroll
        for (int g = 0; g < 2; ++g) {
            const int pl = g * 32 + wv * 8 + psub;
            const unsigned u00[4] = {G00[g].x, G00[g].y, G00[g].z, G00[g].w};
            const unsigned u01[4] = {G01[g].x, G01[g].y, G01[g].z, G01[g].w};
            const unsigned u10[4] = {G10[g].x, G10[g].y, G10[g].z, G10[g].w};
            const unsigned u11[4] = {G11[g].x, G11[g].y, G11[g].z, G11[g].w};
            unsigned pk[4];
            #pragma unroll
            for (int d = 0; d < 4; ++d) {
                const f32x2 c00 = {blo(u00[d]), bhi(u00[d])};
                const f32x2 c01 = {blo(u01[d]), bhi(u01[d])};
                const f32x2 c10 = {blo(u10[d]), bhi(u10[d])};
                const f32x2 c11 = {blo(u11[d]), bhi(u11[d])};
                const f32x2 s = W00[g] * c00 + W01[g] * c01
                              + W10[g] * c10 + W11[g] * c11;
                pk[d] = pack_bf2(s.x, s.y);
            }
            smp4[buf][pl * 8 + (chunk ^ (pl & 7))] =
                make_uint4(pk[0], pk[1], pk[2], pk[3]);
        }
    };

    // prologue: tap 0 into buf 0
    prep(0);
    blendwrite(0);
    __syncthreads();

    #pragma unroll
    for (int k = 0; k < Kn; ++k) {
        const int cur = k & 1;

        if (k < Kn - 1) prep(k + 1);     // gathers in flight during MFMA

        const uint4* wpk = wprep + (size_t)((wv * 9 + k) * 2) * 64 + lane;
        const bf16x8 a0 = __builtin_bit_cast(bf16x8, wpk[0]);
        const bf16x8 a1 = __builtin_bit_cast(bf16x8, wpk[64]);

        #pragma unroll
        for (int nt = 0; nt < 4; ++nt) {
            const int pm = nt * 16 + lrow;
            const bf16x8 b0 = __builtin_bit_cast(bf16x8,
                smp4[cur][pm * 8 + ( quad      ^ (pm & 7))]);
            const bf16x8 b1 = __builtin_bit_cast(bf16x8,
                smp4[cur][pm * 8 + ((quad + 4) ^ (pm & 7))]);
            acc[nt] = __builtin_amdgcn_mfma_f32_16x16x32_bf16(a0, b0, acc[nt], 0, 0, 0);
            acc[nt] = __builtin_amdgcn_mfma_f32_16x16x32_bf16(a1, b1, acc[nt], 0, 0, 0);
        }

        if (k < Kn - 1) blendwrite(cur ^ 1);
        __syncthreads();                  // one barrier per tap
    }

    const int obase = (wv << 4) + (quad << 2);
    #pragma unroll
    for (int nt = 0; nt < 4; ++nt) {
        const int pp = pix0 + nt * 16 + lrow;
        #pragma unroll
        for (int r = 0; r < 4; ++r)
            out[(size_t)(bb * CO_ + obase + r) * HW + pp] = acc[nt][r];
    }
}

extern "C" void kernel_launch(void* const* d_in, const int* in_sizes, int n_in,
                              void* d_out, int out_size, void* d_ws, size_t ws_size,
                              hipStream_t stream) {
    const float* mem   = (const float*)d_in[0];
    const float* que   = (const float*)d_in[1];
    const float* w_off = (const float*)d_in[2];
    const float* b_off = (const float*)d_in[3];
    const float* w_def = (const float*)d_in[4];
    float* out = (float*)d_out;

    char* ws = (char*)d_ws;
    float*          off  = (float*)ws;                         // 14,155,776 B
    unsigned short* wpd  = (unsigned short*)(ws + 14155776);   //     73,728 B
    unsigned short* wpo  = (unsigned short*)(ws + 14229504);   //     73,728 B
    uint4*          xT4  = (uint4*)(ws + 14303232);            // 33,554,432 B

    transpose_kernel<<<2048, 256, 0, stream>>>(mem, que, xT4);
    wprep_def_kernel<<<144, 256, 0, stream>>>(w_def, wpd);
    wprep_off_kernel<<<144, 256, 0, stream>>>(w_off, wpo);
    off_conv_mfma<<<2048, 256, 0, stream>>>(xT4, (const uint4*)wpo, b_off, off);
    deform_mfma_kernel<<<2048, 256, 0, stream>>>(xT4, off, (const uint4*)wpd, out);
}

// Round 9
// 168.836 us; speedup vs baseline: 4.8715x; 1.1011x over previous
//
#include <hip/hip_runtime.h>
#include <hip/hip_fp16.h>

#define Bn   8
#define CM_  64
#define CIN  128   // mem(64) + que(64)
#define CO_  64
#define Hn   128
#define Wn   128
#define Kn   9
#define COFF 27    // 18 offset + 9 mask channels
#define HW   (Hn * Wn)

typedef __attribute__((ext_vector_type(8))) _Float16 f16x8;  // 8 f16 = 4 VGPRs
typedef __attribute__((ext_vector_type(4))) float f32x4;

__device__ __forceinline__ unsigned h22u(__half2 h) {
    unsigned u; __builtin_memcpy(&u, &h, 4); return u;
}
__device__ __forceinline__ __half2 u2h2(unsigned u) {
    __half2 h; __builtin_memcpy(&h, &u, 4); return h;
}
__device__ __forceinline__ unsigned short f2h(float x) {
    __half h = __float2half(x);
    unsigned short u; __builtin_memcpy(&u, &h, 2); return u;
}

// ---------------------------------------------------------------------------
// Kernel T: transpose concat(mem,que) [b][c][px] fp32 -> xT[b][px][c] f16.
// ---------------------------------------------------------------------------
__global__ __launch_bounds__(256) void transpose_kernel(
    const float* __restrict__ mem, const float* __restrict__ que,
    uint4* __restrict__ xT4)
{
    __shared__ unsigned tile[64 * 65];

    const int bb   = blockIdx.x & 7;
    const int pix0 = (blockIdx.x >> 3) * 64;
    const int tid  = threadIdx.x;
    const int pxL  = tid & 63;
    const int cg   = tid >> 6;

    const float* mb = mem + (size_t)bb * CM_ * HW + pix0 + pxL;
    const float* qb = que + (size_t)bb * CM_ * HW + pix0 + pxL;

    #pragma unroll
    for (int i = 0; i < 16; ++i) {
        const int c = cg * 32 + 2 * i;
        const float v0 = (c < CM_) ? mb[(size_t)c * HW]       : qb[(size_t)(c - CM_) * HW];
        const float v1 = (c + 1 < CM_) ? mb[(size_t)(c + 1) * HW] : qb[(size_t)(c + 1 - CM_) * HW];
        tile[pxL * 65 + cg * 16 + i] = h22u(__floats2half2_rn(v0, v1));
    }
    __syncthreads();

    uint4* dst = xT4 + (size_t)(bb * HW + pix0) * 16;
    #pragma unroll
    for (int p = 0; p < 4; ++p) {
        const int G  = p * 256 + tid;
        const int px = G >> 4;
        const int u  = G & 15;
        uint4 v;
        v.x = tile[px * 65 + u * 4 + 0];
        v.y = tile[px * 65 + u * 4 + 1];
        v.z = tile[px * 65 + u * 4 + 2];
        v.w = tile[px * 65 + u * 4 + 3];
        dst[G] = v;
    }
}

// ---------------------------------------------------------------------------
// Kernel W: pack w_def AND w_off into MFMA A-fragment order (f16), one launch.
//   wpd: idx = (((g*9+k)*2+f)*64+L)*8+j  -> W[o=g*16+(L&15)][c=f*32+(L>>4)*8+j], tap k
//   wpo: idx = (((ot*9+tap)*4+s)*64+L)*8+j -> o=ot*16+(L&15) (pad 27->32), c=s*32+...
// ---------------------------------------------------------------------------
__global__ __launch_bounds__(256) void wprep_all_kernel(
    const float* __restrict__ w_def, const float* __restrict__ w_off,
    unsigned short* __restrict__ wpd, unsigned short* __restrict__ wpo)
{
    int idx = blockIdx.x * 256 + threadIdx.x;
    if (idx < CO_ * CM_ * Kn) {
        const int j  = idx & 7;
        const int L  = (idx >> 3) & 63;
        const int f  = (idx >> 9) & 1;
        const int gk = idx >> 10;
        const int k  = gk % 9;
        const int g  = gk / 9;
        const int o  = g * 16 + (L & 15);
        const int c  = f * 32 + (L >> 4) * 8 + j;
        wpd[idx] = f2h(w_def[(size_t)(o * CM_ + c) * Kn + k]);
        return;
    }
    idx -= CO_ * CM_ * Kn;
    if (idx < 2 * 9 * 4 * 64 * 8) {
        const int j   = idx & 7;
        const int L   = (idx >> 3) & 63;
        const int s   = (idx >> 9) & 3;
        const int r   = idx >> 11;
        const int tap = r % 9;
        const int ot  = r / 9;
        const int o   = ot * 16 + (L & 15);
        const int c   = s * 32 + (L >> 4) * 8 + j;
        wpo[idx] = (o < COFF) ? f2h(w_off[(size_t)(o * CIN + c) * Kn + tap])
                              : (unsigned short)0;
    }
}

// ---------------------------------------------------------------------------
// Fused kernel: offset-conv GEMM (phase 1, off -> LDS only) + deformable
// sampling + deform GEMM (phase 2). Block = 64-px row strip, all 64 outs.
// LDS union (50,688 B -> 3 blocks/CU):
//   phase 1 : xw[198 slots][16 chunks] window (3 rows x 66 cols, f16x8 chunks)
//   phase 2 : offl[27][64] fp32 at offset 0; smp4[2][64][8] at offset 8192.
// ---------------------------------------------------------------------------
__global__ __launch_bounds__(256) void fused_deform_kernel(
    const uint4* __restrict__ xT4, const uint4* __restrict__ wpo,
    const uint4* __restrict__ wpd, const float* __restrict__ b_off,
    float* __restrict__ out)
{
    __shared__ __align__(16) char lds[198 * 16 * 16];   // 50,688 B
    uint4* xw   = (uint4*)lds;
    float* offl = (float*)lds;                          // 27*64*4 = 6,912 B
    uint4* smp4 = (uint4*)(lds + 8192);                 // 2*64*8*16 = 16,384 B

    const int bb   = blockIdx.x & 7;                    // batch -> XCD affinity
    const int pix0 = (blockIdx.x >> 3) * 64;
    const int h0   = pix0 >> 7;
    const int w0   = pix0 & 127;
    const int tid  = threadIdx.x;
    const int wv   = tid >> 6;
    const int lane = tid & 63;
    const int quad = lane >> 4;
    const int lrow = lane & 15;

    const uint4* xb = xT4 + (size_t)bb * HW * 16;

    // ======== phase 1: stage 3x66 window ========
    #pragma unroll
    for (int g = 0; g < 13; ++g) {
        const int idx = g * 256 + tid;
        if (idx < 198 * 16) {
            const int slot = idx >> 4;
            const int j    = idx & 15;
            const int r    = slot / 66;
            const int c    = slot - r * 66;
            const int y    = h0 + r - 1;
            const int x    = w0 + c - 1;
            const bool ok  = (y >= 0) & (y < Hn) & (x >= 0) & (x < Wn);
            uint4 v = make_uint4(0, 0, 0, 0);
            if (ok) v = xb[(size_t)(y * Wn + x) * 16 + j];
            xw[slot * 16 + (j ^ (slot & 7))] = v;
        }
    }
    __syncthreads();

    // ======== phase 1: offset-conv GEMM ========
    {
        const int ot   = wv >> 1;
        const int sub0 = (wv & 1) * 2;

        f32x4 oacc[2];
        #pragma unroll
        for (int t = 0; t < 2; ++t)
            #pragma unroll
            for (int r = 0; r < 4; ++r) {
                const int o = ot * 16 + quad * 4 + r;
                oacc[t][r] = (o < COFF) ? b_off[o] : 0.0f;
            }

        #pragma unroll
        for (int tap = 0; tap < 9; ++tap) {
            const int rr = tap / 3;
            const int cc = tap % 3;

            const uint4* ap = wpo + (size_t)((ot * 9 + tap) * 4) * 64 + lane;
            f16x8 a[4];
            #pragma unroll
            for (int s = 0; s < 4; ++s)
                a[s] = __builtin_bit_cast(f16x8, ap[s * 64]);

            #pragma unroll
            for (int t = 0; t < 2; ++t) {
                const int pl   = (sub0 + t) * 16 + lrow;
                const int slot = rr * 66 + pl + cc;
                const int base = slot * 16;
                const int sw   = slot & 7;
                #pragma unroll
                for (int s = 0; s < 4; ++s) {
                    const f16x8 bfrag = __builtin_bit_cast(f16x8,
                        xw[base + ((s * 4 + quad) ^ sw)]);
                    oacc[t] = __builtin_amdgcn_mfma_f32_16x16x32_f16(
                        a[s], bfrag, oacc[t], 0, 0, 0);
                }
            }
        }
        __syncthreads();   // all xw reads complete before offl overwrite

        #pragma unroll
        for (int t = 0; t < 2; ++t) {
            const int pl = (sub0 + t) * 16 + lrow;
            #pragma unroll
            for (int r = 0; r < 4; ++r) {
                const int o = ot * 16 + quad * 4 + r;
                if (o < COFF) offl[o * 64 + pl] = oacc[t][r];
            }
        }
        __syncthreads();   // offl visible to all
    }

    // ======== phase 2: deformable sampling + deform GEMM ========
    const int chunk = lane & 7;
    const int psub  = lane >> 3;

    const int pM = pix0 + lane;        // pixel-major identity (lane = pixel)
    const int hM = pM >> 7;
    const int wM = pM & 127;

    f32x4 acc[4];
    #pragma unroll
    for (int i = 0; i < 4; ++i) acc[i] = (f32x4){0.f, 0.f, 0.f, 0.f};

    __half2 W00h[2], W01h[2], W10h[2], W11h[2];
    uint4   G00[2], G01[2], G10[2], G11[2];

    auto prep = [&](int k) {
        const float dy = offl[(2 * k    ) * 64 + lane];
        const float dx = offl[(2 * k + 1) * 64 + lane];
        const float mk = offl[(18 + k   ) * 64 + lane];
        const float py = (float)(hM + k / 3 - 1) + dy;
        const float px = (float)(wM + k % 3 - 1) + dx;
        const float y0f = floorf(py), x0f = floorf(px);
        const float fy = py - y0f,  fx = px - x0f;
        const int y0 = (int)y0f, x0 = (int)x0f;
        const int y1 = y0 + 1,   x1 = x0 + 1;
        const bool vy0 = (y0 >= 0) & (y0 < Hn);
        const bool vy1 = (y1 >= 0) & (y1 < Hn);
        const bool vx0 = (x0 >= 0) & (x0 < Wn);
        const bool vx1 = (x1 >= 0) & (x1 < Wn);
        const float w00 = (1.f - fy) * (1.f - fx) * (float)(vy0 & vx0) * mk;
        const float w01 = (1.f - fy) * fx         * (float)(vy0 & vx1) * mk;
        const float w10 = fy * (1.f - fx)         * (float)(vy1 & vx0) * mk;
        const float w11 = fy * fx                 * (float)(vy1 & vx1) * mk;
        const int y0c = min(max(y0, 0), Hn - 1);
        const int y1c = min(max(y1, 0), Hn - 1);
        const int x0c = min(max(x0, 0), Wn - 1);
        const int x1c = min(max(x1, 0), Wn - 1);
        const int i00 = y0c * Wn + x0c, i01 = y0c * Wn + x1c;
        const int i10 = y1c * Wn + x0c, i11 = y1c * Wn + x1c;

        #pragma unroll
        for (int g = 0; g < 2; ++g) {
            const int pl = g * 32 + wv * 8 + psub;
            W00h[g] = __float2half2_rn(__shfl(w00, pl, 64));
            W01h[g] = __float2half2_rn(__shfl(w01, pl, 64));
            W10h[g] = __float2half2_rn(__shfl(w10, pl, 64));
            W11h[g] = __float2half2_rn(__shfl(w11, pl, 64));
            const int I00 = __shfl(i00, pl, 64);
            const int I01 = __shfl(i01, pl, 64);
            const int I10 = __shfl(i10, pl, 64);
            const int I11 = __shfl(i11, pl, 64);
            G00[g] = xb[(size_t)I00 * 16 + chunk];
            G01[g] = xb[(size_t)I01 * 16 + chunk];
            G10[g] = xb[(size_t)I10 * 16 + chunk];
            G11[g] = xb[(size_t)I11 * 16 + chunk];
        }
    };

    auto blendwrite = [&](int buf) {
        #pragma unroll
        for (int g = 0; g < 2; ++g) {
            const int pl = g * 32 + wv * 8 + psub;
            const unsigned u00[4] = {G00[g].x, G00[g].y, G00[g].z, G00[g].w};
            const unsigned u01[4] = {G01[g].x, G01[g].y, G01[g].z, G01[g].w};
            const unsigned u10[4] = {G10[g].x, G10[g].y, G10[g].z, G10[g].w};
            const unsigned u11[4] = {G11[g].x, G11[g].y, G11[g].z, G11[g].w};
            unsigned pk[4];
            #pragma unroll
            for (int d = 0; d < 4; ++d) {
                __half2 s = __hmul2(u2h2(u00[d]), W00h[g]);
                s = __hfma2(u2h2(u01[d]), W01h[g], s);
                s = __hfma2(u2h2(u10[d]), W10h[g], s);
                s = __hfma2(u2h2(u11[d]), W11h[g], s);
                pk[d] = h22u(s);
            }
            smp4[buf * 512 + pl * 8 + (chunk ^ (pl & 7))] =
                make_uint4(pk[0], pk[1], pk[2], pk[3]);
        }
    };

    prep(0);
    blendwrite(0);
    __syncthreads();

    #pragma unroll
    for (int k = 0; k < Kn; ++k) {
        const int cur = k & 1;

        if (k < Kn - 1) prep(k + 1);     // gathers in flight during MFMA

        const uint4* wpk = wpd + (size_t)((wv * 9 + k) * 2) * 64 + lane;
        const f16x8 a0 = __builtin_bit_cast(f16x8, wpk[0]);
        const f16x8 a1 = __builtin_bit_cast(f16x8, wpk[64]);

        #pragma unroll
        for (int nt = 0; nt < 4; ++nt) {
            const int pm = nt * 16 + lrow;
            const f16x8 b0 = __builtin_bit_cast(f16x8,
                smp4[cur * 512 + pm * 8 + ( quad      ^ (pm & 7))]);
            const f16x8 b1 = __builtin_bit_cast(f16x8,
                smp4[cur * 512 + pm * 8 + ((quad + 4) ^ (pm & 7))]);
            acc[nt] = __builtin_amdgcn_mfma_f32_16x16x32_f16(a0, b0, acc[nt], 0, 0, 0);
            acc[nt] = __builtin_amdgcn_mfma_f32_16x16x32_f16(a1, b1, acc[nt], 0, 0, 0);
        }

        if (k < Kn - 1) blendwrite(cur ^ 1);
        __syncthreads();
    }

    const int obase = (wv << 4) + (quad << 2);
    #pragma unroll
    for (int nt = 0; nt < 4; ++nt) {
        const int pp = pix0 + nt * 16 + lrow;
        #pragma unroll
        for (int r = 0; r < 4; ++r)
            out[(size_t)(bb * CO_ + obase + r) * HW + pp] = acc[nt][r];
    }
}

extern "C" void kernel_launch(void* const* d_in, const int* in_sizes, int n_in,
                              void* d_out, int out_size, void* d_ws, size_t ws_size,
                              hipStream_t stream) {
    const float* mem   = (const float*)d_in[0];
    const float* que   = (const float*)d_in[1];
    const float* w_off = (const float*)d_in[2];
    const float* b_off = (const float*)d_in[3];
    const float* w_def = (const float*)d_in[4];
    float* out = (float*)d_out;

    char* ws = (char*)d_ws;
    unsigned short* wpd = (unsigned short*)ws;             //  73,728 B
    unsigned short* wpo = (unsigned short*)(ws + 73728);   //  73,728 B
    uint4*          xT4 = (uint4*)(ws + 147456);           //  33,554,432 B

    transpose_kernel<<<2048, 256, 0, stream>>>(mem, que, xT4);
    wprep_all_kernel<<<288, 256, 0, stream>>>(w_def, w_off, wpd, wpo);
    fused_deform_kernel<<<2048, 256, 0, stream>>>(
        xT4, (const uint4*)wpo, (const uint4*)wpd, b_off, out);
}